// Round 6
// baseline (279.187 us; speedup 1.0000x reference)
//
#include <hip/hip_runtime.h>
#include <hip/hip_bf16.h>
#include <stdint.h>

// Shapes (fixed for this problem)
#define TOKENS 8192   // b*s = 4*2048
#define H 2048
#define JDIM 2048
#define NADAPT 64
#define RANK 16
#define KG 1024       // NADAPT*RANK
#define KTOT 3072     // H + KG
#define NT2 48        // gemm2 K-tiles = KTOT/64
#define CAP 2048      // flagged-token capacity
#define EPS 0.01f     // top-4/5 norm-gap margin (fp16 arrow err sigma ~6e-4 -> 11 sigma)

typedef __bf16 v8bf __attribute__((ext_vector_type(8)));
typedef _Float16 v8hf __attribute__((ext_vector_type(8)));
typedef float v4f __attribute__((ext_vector_type(4)));
typedef unsigned short us8 __attribute__((ext_vector_type(8)));
typedef unsigned short us4 __attribute__((ext_vector_type(4)));

__device__ __forceinline__ unsigned short f2bf(float f) {
  union { __bf16 b; unsigned short u; } c; c.b = (__bf16)f; return c.u;
}
__device__ __forceinline__ float bf2f(unsigned short u) {
  union { unsigned int u; float f; } c; c.u = ((unsigned int)u) << 16; return c.f;
}

__device__ __forceinline__ us8 pack8(float4 a, float4 b) {
  us8 r;
  r[0]=f2bf(a.x); r[1]=f2bf(a.y); r[2]=f2bf(a.z); r[3]=f2bf(a.w);
  r[4]=f2bf(b.x); r[5]=f2bf(b.y); r[6]=f2bf(b.z); r[7]=f2bf(b.w);
  return r;
}

__device__ __forceinline__ void split4(float4 v, us4& h, us4& l) {
  h[0]=f2bf(v.x); l[0]=f2bf(v.x - bf2f(h[0]));
  h[1]=f2bf(v.y); l[1]=f2bf(v.y - bf2f(h[1]));
  h[2]=f2bf(v.z); l[2]=f2bf(v.z - bf2f(h[2]));
  h[3]=f2bf(v.w); l[3]=f2bf(v.w - bf2f(h[3]));
}

// x fp32 [8192][2048] -> bf16 hi into XG (stride KTOT) + fp16 into Xf (stride 2048).
__global__ void cast_x_kernel(const float* __restrict__ x,
                              unsigned short* __restrict__ XG,
                              _Float16* __restrict__ Xf) {
  int idx = blockIdx.x * 256 + threadIdx.x;
  int row = idx >> 8, cg = idx & 255;
  const float4* s = (const float4*)(x + ((size_t)row << 11) + ((size_t)cg << 3));
  float4 a = s[0], b = s[1];
  float v[8] = {a.x, a.y, a.z, a.w, b.x, b.y, b.z, b.w};
  us8 h; v8hf f;
  #pragma unroll
  for (int i = 0; i < 8; ++i) { h[i] = f2bf(v[i]); f[i] = (_Float16)v[i]; }
  *(us8*)(XG + (size_t)row * KTOT + ((size_t)cg << 3)) = h;
  *(v8hf*)(Xf + ((size_t)row << 11) + ((size_t)cg << 3)) = f;
}

// A fp32 [1024][2048] -> Af16 fp16 + Ahi/Alo bf16 (for exact recompute). Zeroes counter.
__global__ void cast_a_kernel(const float* __restrict__ A,
                              _Float16* __restrict__ Af,
                              unsigned short* __restrict__ Ahi,
                              unsigned short* __restrict__ Alo,
                              int* __restrict__ cnt) {
  if (blockIdx.x == 0 && threadIdx.x == 0) *cnt = 0;
  int idx = blockIdx.x * 256 + threadIdx.x;
  int row = idx >> 8, cg = idx & 255;
  const float4* s = (const float4*)(A + ((size_t)row << 11) + ((size_t)cg << 3));
  float4 a = s[0], b = s[1];
  us4 h0, l0, h1, l1;
  split4(a, h0, l0);
  split4(b, h1, l1);
  v8hf f;
  float v[8] = {a.x, a.y, a.z, a.w, b.x, b.y, b.z, b.w};
  #pragma unroll
  for (int i = 0; i < 8; ++i) f[i] = (_Float16)v[i];
  size_t o = ((size_t)row << 11) + ((size_t)cg << 3);
  *(v8hf*)(Af + o) = f;
  *(us4*)(Ahi + o) = h0; *(us4*)(Ahi + o + 4) = h1;
  *(us4*)(Alo + o) = l0; *(us4*)(Alo + o + 4) = l1;
}

// fp32 [rows][2048] -> bf16 [rows][dstld] (fills cols 0..2047).
__global__ void cast2048_kernel(const float* __restrict__ src,
                                unsigned short* __restrict__ dst, int dstld) {
  int idx = blockIdx.x * 256 + threadIdx.x;
  int row = idx >> 8;
  int cg  = idx & 255;
  const float4* s = (const float4*)(src + ((size_t)row << 11) + ((size_t)cg << 3));
  float4 a = s[0], b = s[1];
  *(us8*)(dst + (size_t)row * dstld + ((size_t)cg << 3)) = pack8(a, b);
}

// B [64][2048][16] fp32 -> WB[j][2048 + a*16 + r] bf16. One thread per (a,j).
__global__ void cast_b_kernel(const float* __restrict__ Bsrc,
                              unsigned short* __restrict__ WB) {
  int idx = blockIdx.x * 256 + threadIdx.x;   // 131072 total
  int a = idx >> 11, j = idx & 2047;
  const float4* s = (const float4*)(Bsrc + (((size_t)a << 11) + j) * RANK);
  float4 f0 = s[0], f1 = s[1], f2 = s[2], f3 = s[3];
  us8* d = (us8*)(WB + (size_t)j * KTOT + H + a * RANK);
  d[0] = pack8(f0, f1);
  d[1] = pack8(f2, f3);
}

// Per token: arrows from fp16-precision vecs, top-4, G row; flag tokens whose
// 4th/5th norm gap < EPS for exact recompute.
__global__ void route_kernel(const float* __restrict__ vecs,
                             unsigned short* __restrict__ XG,
                             int* __restrict__ cnt, int* __restrict__ tokidx) {
  __shared__ float vsh[4][16];
  int wave = threadIdx.x >> 6, lane = threadIdx.x & 63;
  int t = blockIdx.x * 4 + wave;
  const float* vrow = vecs + (size_t)t * KG;
  const float4* vp = (const float4*)(vrow + lane * RANK);
  float4 q0 = vp[0], q1 = vp[1], q2 = vp[2], q3 = vp[3];
  float ss = q0.x*q0.x + q0.y*q0.y + q0.z*q0.z + q0.w*q0.w
           + q1.x*q1.x + q1.y*q1.y + q1.z*q1.z + q1.w*q1.w
           + q2.x*q2.x + q2.y*q2.y + q2.z*q2.z + q2.w*q2.w
           + q3.x*q3.x + q3.y*q3.y + q3.z*q3.z + q3.w*q3.w;
  float arr = ss;
  int sel[4];
  float v4 = 0.f, v5 = 0.f;
  #pragma unroll
  for (int k = 0; k < 5; ++k) {
    float m = arr; int mi = lane;
    #pragma unroll
    for (int o = 32; o > 0; o >>= 1) {
      float om = __shfl_xor(m, o);
      int oi  = __shfl_xor(mi, o);
      if (om > m || (om == m && oi < mi)) { m = om; mi = oi; }
    }
    if (k < 4) {
      sel[k] = mi;                 // wave-uniform
      if (lane == mi) arr = -3.0e38f;
    }
    if (k == 3) v4 = m;
    if (k == 4) v5 = m;
  }
  bool flag = (sqrtf(v4) - sqrtf(v5)) < EPS;
  if (flag && lane == 0) {
    int p = atomicAdd(cnt, 1);
    if (p < CAP) tokidx[p] = t;
  }
  if (lane < 16) {
    float s = vrow[sel[0]*RANK + lane] + vrow[sel[1]*RANK + lane]
            + vrow[sel[2]*RANK + lane] + vrow[sel[3]*RANK + lane];
    vsh[wave][lane] = 0.0625f * s;
  }
  __syncthreads();
  bool on = (lane == sel[0]) | (lane == sel[1]) | (lane == sel[2]) | (lane == sel[3]);
  us8 lo, hi;
  #pragma unroll
  for (int r = 0; r < 8; ++r) lo[r] = on ? f2bf(vsh[wave][r])     : (unsigned short)0;
  #pragma unroll
  for (int r = 0; r < 8; ++r) hi[r] = on ? f2bf(vsh[wave][r + 8]) : (unsigned short)0;
  us8* d = (us8*)(XG + (size_t)t * KTOT + H + lane * RANK);
  d[0] = lo; d[1] = hi;
}

__device__ __forceinline__ void gload_lds16(const void* gsrc, void* ldst) {
  __builtin_amdgcn_global_load_lds(
      (const __attribute__((address_space(1))) unsigned int*)gsrc,
      (__attribute__((address_space(3))) unsigned int*)ldst, 16, 0, 0);
}

// ------------------------------------------------------------------
// GEMM1 (fp16): vecs[8192,1024] = Xf16 @ Af16^T. 128x128 tile, 4 waves, BK=32,
// global_load_lds staging, swizzle: 16B slot ^= (row>>1)&3 (src + read sides).
// ------------------------------------------------------------------
__global__ __launch_bounds__(256, 2) void gemm1f16_kernel(
    const _Float16* __restrict__ Xf, const _Float16* __restrict__ Af,
    float* __restrict__ C) {
  __shared__ _Float16 As[128 * 32];
  __shared__ _Float16 Bs[128 * 32];
  const int tid = threadIdx.x;
  const int lane = tid & 63, wave = tid >> 6;
  const int wr = wave >> 1, wc = wave & 1;
  const int bm = blockIdx.x, bn = blockIdx.y;

  v4f acc[4][4];
  #pragma unroll
  for (int i = 0; i < 4; ++i)
    #pragma unroll
    for (int j = 0; j < 4; ++j)
      acc[i][j] = (v4f){0.f, 0.f, 0.f, 0.f};

  const _Float16* Abase = Xf + ((size_t)(bm * 128) << 11);
  const _Float16* Bbase = Af + ((size_t)(bn * 128) << 11);

  const int rA = lane & 15;
  const int kkx = (((lane >> 4) ^ ((rA >> 1) & 3)) << 3);

  for (int k0 = 0; k0 < H; k0 += 32) {
    #pragma unroll
    for (int rnd = 0; rnd < 2; ++rnd) {
      int e = rnd * 256 + tid;
      int r = e >> 2;
      int c8 = (((e & 3) ^ ((e >> 3) & 3)) << 3);   // pre-swizzled source slot
      gload_lds16(Abase + ((size_t)r << 11) + k0 + c8, (char*)As + (size_t)e * 16);
      gload_lds16(Bbase + ((size_t)r << 11) + k0 + c8, (char*)Bs + (size_t)e * 16);
    }
    __syncthreads();
    v8hf af[4], bfr[4];
    #pragma unroll
    for (int i = 0; i < 4; ++i)
      af[i] = *(const v8hf*)&As[(wr * 64 + i * 16 + rA) * 32 + kkx];
    #pragma unroll
    for (int j = 0; j < 4; ++j)
      bfr[j] = *(const v8hf*)&Bs[(wc * 64 + j * 16 + rA) * 32 + kkx];
    #pragma unroll
    for (int i = 0; i < 4; ++i)
      #pragma unroll
      for (int j = 0; j < 4; ++j)
        acc[i][j] = __builtin_amdgcn_mfma_f32_16x16x32_f16(af[i], bfr[j], acc[i][j], 0, 0, 0);
    __syncthreads();
  }

  const int rowbase = bm * 128 + wr * 64;
  const int colbase = bn * 128 + wc * 64;
  #pragma unroll
  for (int i = 0; i < 4; ++i) {
    int r0 = rowbase + i * 16 + ((lane >> 4) << 2);
    #pragma unroll
    for (int j = 0; j < 4; ++j) {
      int col = colbase + j * 16 + (lane & 15);
      #pragma unroll
      for (int q = 0; q < 4; ++q)
        C[(size_t)(r0 + q) * KG + col] = acc[i][j][q];
    }
  }
}

// ------------------------------------------------------------------
// Exact recompute for flagged tokens: vecs[tok,:] = x[tok]@A^T via 3-term bf16
// split (Xhi@Ahi + Xhi@Alo + Xlo@Ahi). Gathered A-rows (reg-staged on-the-fly
// split), B from pre-split Ahi/Alo via gload. 128x128 tile, BK=32.
// ------------------------------------------------------------------
__global__ __launch_bounds__(256, 2) void regemm_kernel(
    const float* __restrict__ x, const unsigned short* __restrict__ Ahi,
    const unsigned short* __restrict__ Alo, float* __restrict__ vecs,
    const int* __restrict__ cnt, const int* __restrict__ tokidx) {
  int cn = *cnt; if (cn > CAP) cn = CAP;
  const int mblk = blockIdx.x;
  if (mblk * 128 >= cn) return;

  __shared__ unsigned short AsH[128 * 32];
  __shared__ unsigned short AsL[128 * 32];
  __shared__ unsigned short BsH[128 * 32];
  __shared__ unsigned short BsL[128 * 32];
  __shared__ int toks[128];

  const int tid = threadIdx.x;
  if (tid < 128) {
    int m = mblk * 128 + tid;
    toks[tid] = (m < cn) ? tokidx[m] : tokidx[0];
  }
  __syncthreads();

  const int lane = tid & 63, wave = tid >> 6;
  const int wr = wave >> 1, wc = wave & 1;
  const int bn = blockIdx.y;

  v4f acc[4][4];
  #pragma unroll
  for (int i = 0; i < 4; ++i)
    #pragma unroll
    for (int j = 0; j < 4; ++j)
      acc[i][j] = (v4f){0.f, 0.f, 0.f, 0.f};

  const unsigned short* AhiB = Ahi + ((size_t)(bn * 128) << 11);
  const unsigned short* AloB = Alo + ((size_t)(bn * 128) << 11);
  const int rA = lane & 15;
  const int kk = (lane >> 4) << 3;

  for (int k0 = 0; k0 < H; k0 += 32) {
    // X staging: gathered fp32 rows, on-the-fly hi/lo split
    #pragma unroll
    for (int rnd = 0; rnd < 4; ++rnd) {
      int u = rnd * 256 + tid;
      int r = u >> 3, c4 = (u & 7) << 2;
      float4 xv = *(const float4*)(x + ((size_t)toks[r] << 11) + k0 + c4);
      us4 xh, xl;
      split4(xv, xh, xl);
      *(us4*)&AsH[r * 32 + c4] = xh;
      *(us4*)&AsL[r * 32 + c4] = xl;
    }
    // B staging: pre-split bf16 panels
    #pragma unroll
    for (int rnd = 0; rnd < 2; ++rnd) {
      int e = rnd * 256 + tid;
      int r = e >> 2, c8 = (e & 3) << 3;
      gload_lds16(AhiB + ((size_t)r << 11) + k0 + c8, (char*)BsH + (size_t)e * 16);
      gload_lds16(AloB + ((size_t)r << 11) + k0 + c8, (char*)BsL + (size_t)e * 16);
    }
    __syncthreads();
    v8bf ah[4], al[4], bh[4], bl[4];
    #pragma unroll
    for (int i = 0; i < 4; ++i) {
      ah[i] = *(const v8bf*)&AsH[(wr * 64 + i * 16 + rA) * 32 + kk];
      al[i] = *(const v8bf*)&AsL[(wr * 64 + i * 16 + rA) * 32 + kk];
    }
    #pragma unroll
    for (int j = 0; j < 4; ++j) {
      bh[j] = *(const v8bf*)&BsH[(wc * 64 + j * 16 + rA) * 32 + kk];
      bl[j] = *(const v8bf*)&BsL[(wc * 64 + j * 16 + rA) * 32 + kk];
    }
    #pragma unroll
    for (int i = 0; i < 4; ++i)
      #pragma unroll
      for (int j = 0; j < 4; ++j) {
        acc[i][j] = __builtin_amdgcn_mfma_f32_16x16x32_bf16(ah[i], bh[j], acc[i][j], 0, 0, 0);
        acc[i][j] = __builtin_amdgcn_mfma_f32_16x16x32_bf16(ah[i], bl[j], acc[i][j], 0, 0, 0);
        acc[i][j] = __builtin_amdgcn_mfma_f32_16x16x32_bf16(al[i], bh[j], acc[i][j], 0, 0, 0);
      }
    __syncthreads();
  }

  const int colbase = bn * 128 + wc * 64;
  #pragma unroll
  for (int i = 0; i < 4; ++i) {
    int lr0 = wr * 64 + i * 16 + ((lane >> 4) << 2);
    #pragma unroll
    for (int j = 0; j < 4; ++j) {
      int col = colbase + j * 16 + rA;
      #pragma unroll
      for (int q = 0; q < 4; ++q) {
        int lr = lr0 + q;
        if (mblk * 128 + lr < cn)
          vecs[(size_t)toks[lr] * KG + col] = acc[i][j][q];
      }
    }
  }
}

// Re-route flagged tokens from exact vecs (barrier-free; one wave per token).
__global__ void route_fix_kernel(const float* __restrict__ vecs,
                                 unsigned short* __restrict__ XG,
                                 const int* __restrict__ cnt,
                                 const int* __restrict__ tokidx) {
  int cn = *cnt; if (cn > CAP) cn = CAP;
  int i = blockIdx.x * 4 + (threadIdx.x >> 6);
  if (i >= cn) return;
  int lane = threadIdx.x & 63;
  int t = tokidx[i];
  const float* vrow = vecs + (size_t)t * KG;
  const float4* vp = (const float4*)(vrow + lane * RANK);
  float4 q0 = vp[0], q1 = vp[1], q2 = vp[2], q3 = vp[3];
  float ss = q0.x*q0.x + q0.y*q0.y + q0.z*q0.z + q0.w*q0.w
           + q1.x*q1.x + q1.y*q1.y + q1.z*q1.z + q1.w*q1.w
           + q2.x*q2.x + q2.y*q2.y + q2.z*q2.z + q2.w*q2.w
           + q3.x*q3.x + q3.y*q3.y + q3.z*q3.z + q3.w*q3.w;
  float arr = ss;
  int sel[4];
  #pragma unroll
  for (int k = 0; k < 4; ++k) {
    float m = arr; int mi = lane;
    #pragma unroll
    for (int o = 32; o > 0; o >>= 1) {
      float om = __shfl_xor(m, o);
      int oi  = __shfl_xor(mi, o);
      if (om > m || (om == m && oi < mi)) { m = om; mi = oi; }
    }
    sel[k] = mi;
    if (lane == mi) arr = -3.0e38f;
  }
  int r = lane & 15;
  float g = 0.0625f * (vrow[sel[0]*RANK + r] + vrow[sel[1]*RANK + r]
                     + vrow[sel[2]*RANK + r] + vrow[sel[3]*RANK + r]);
  bool on = (lane == sel[0]) | (lane == sel[1]) | (lane == sel[2]) | (lane == sel[3]);
  us8 lo, hi;
  #pragma unroll
  for (int k = 0; k < 8; ++k) {
    float gv = __shfl(g, k);
    lo[k] = on ? f2bf(gv) : (unsigned short)0;
  }
  #pragma unroll
  for (int k = 0; k < 8; ++k) {
    float gv = __shfl(g, k + 8);
    hi[k] = on ? f2bf(gv) : (unsigned short)0;
  }
  us8* d = (us8*)(XG + (size_t)t * KTOT + H + lane * RANK);
  d[0] = lo; d[1] = hi;
}

// ------------------------------------------------------------------
// GEMM2: out[8192,2048] = XG[8192,3072]@WB[2048,3072]^T + bias. (unchanged)
// 256x256 tile, BK=64, 8 waves, 8-phase schedule, counted vmcnt(8), setprio,
// bank swizzle: 16B slot ^= (row>>1)&3 on both stage-src and ds_read.
// ------------------------------------------------------------------
#define BAR() asm volatile("s_waitcnt lgkmcnt(0)\n\ts_barrier" ::: "memory")
#define VM8() asm volatile("s_waitcnt vmcnt(8)" ::: "memory")

#define STAGE(regionUS, panel, kelem) do {                                        \
  gload_lds16((panel) + aoff0 + (kelem), (char*)(regionUS) + tid * 16);           \
  gload_lds16((panel) + aoff1 + (kelem), (char*)(regionUS) + 8192 + tid * 16);    \
} while (0)

#define PHASE(mh, RAr, RBr, ISSUE, DOVM) do {                                     \
  if ((mh) == 0) {                                                                \
    _Pragma("unroll")                                                             \
    for (int j = 0; j < 4; ++j)                                                   \
      bfr[j] = *(const v8bf*)((const char*)(RBr) + bbyte + j * 1024);             \
  }                                                                               \
  _Pragma("unroll")                                                               \
  for (int i = 0; i < 4; ++i)                                                     \
    af[i] = *(const v8bf*)((const char*)(RAr) + abyte + ((mh)*4 + i) * 1024);     \
  ISSUE;                                                                          \
  BAR();                                                                          \
  __builtin_amdgcn_s_setprio(1);                                                  \
  _Pragma("unroll")                                                               \
  for (int i = 0; i < 4; ++i)                                                     \
    _Pragma("unroll")                                                             \
    for (int j = 0; j < 4; ++j)                                                   \
      acc[(mh)*4 + i][j] = __builtin_amdgcn_mfma_f32_16x16x32_bf16(               \
          af[i], bfr[j], acc[(mh)*4 + i][j], 0, 0, 0);                            \
  __builtin_amdgcn_s_setprio(0);                                                  \
  DOVM;                                                                           \
  BAR();                                                                          \
} while (0)

__global__ __launch_bounds__(512, 1) void gemm2_8ph_kernel(
    const unsigned short* __restrict__ Xg, const unsigned short* __restrict__ Wb,
    float* __restrict__ C, const float* __restrict__ bias) {
  __shared__ unsigned short lds[65536];   // 128 KB
  const int tid = threadIdx.x;
  const int lane = tid & 63, wid = tid >> 6;
  const int wr = wid >> 2, wc = wid & 3;
  const int rA = lane & 15, grp = lane >> 4;
  const int grpx = (grp ^ ((rA >> 1) & 3)) << 4;   // swizzled 16B slot (byte)

  const int bid = blockIdx.x;
  const int bn = bid & 7, bm = bid >> 3;           // each XCD owns one bn column

  const unsigned short* Ap = Xg + (size_t)(bm * 256) * KTOT;
  const unsigned short* Bp = Wb + (size_t)(bn * 256) * KTOT;

  const int srow = tid >> 2;
  const int scol = ((tid & 3) ^ ((tid >> 3) & 3)) << 3;
  const size_t aoff0 = (size_t)srow * KTOT + scol;
  const size_t aoff1 = (size_t)(srow + 128) * KTOT + scol;

  unsigned short* A0k0 = lds;
  unsigned short* A0k1 = lds + 8192;
  unsigned short* B0k0 = lds + 16384;
  unsigned short* B0k1 = lds + 24576;
  unsigned short* A1k0 = lds + 32768;
  unsigned short* A1k1 = lds + 40960;
  unsigned short* B1k0 = lds + 49152;
  unsigned short* B1k1 = lds + 57344;

  const int abyte = (wr * 128 + rA) * 64 + grpx;
  const int bbyte = (wc * 64 + rA) * 64 + grpx;

  v4f acc[8][4];
  #pragma unroll
  for (int i = 0; i < 8; ++i)
    #pragma unroll
    for (int j = 0; j < 4; ++j)
      acc[i][j] = (v4f){0.f, 0.f, 0.f, 0.f};
  v8bf af[4], bfr[4];

  STAGE(A0k0, Ap, 0);
  STAGE(B0k0, Bp, 0);
  STAGE(A0k1, Ap, 32);
  STAGE(B0k1, Bp, 32);
  STAGE(A1k0, Ap, 64);
  STAGE(B1k0, Bp, 64);
  VM8();
  BAR();

  #pragma unroll 1
  for (int t = 0; t < NT2; t += 2) {
    const int k1a = (t + 1) * 64 + 32;
    const int k0a = (t + 2 < NT2 ? t + 2 : NT2 - 1) * 64;
    const int k1b = (t + 2 < NT2 ? t + 2 : NT2 - 1) * 64 + 32;
    const int k0b = (t + 3 < NT2 ? t + 3 : NT2 - 1) * 64;
    PHASE(0, A0k0, B0k0, STAGE(A1k1, Ap, k1a), ((void)0));
    PHASE(1, A0k0, B0k0, STAGE(B1k1, Bp, k1a), VM8());
    PHASE(0, A0k1, B0k1, STAGE(A0k0, Ap, k0a), ((void)0));
    PHASE(1, A0k1, B0k1, STAGE(B0k0, Bp, k0a), VM8());
    PHASE(0, A1k0, B1k0, STAGE(A0k1, Ap, k1b), ((void)0));
    PHASE(1, A1k0, B1k0, STAGE(B0k1, Bp, k1b), VM8());
    PHASE(0, A1k1, B1k1, STAGE(A1k0, Ap, k0b), ((void)0));
    PHASE(1, A1k1, B1k1, STAGE(B1k0, Bp, k0b), VM8());
  }

  const int row0 = bm * 256 + wr * 128 + (grp << 2);
  const int col0 = bn * 256 + wc * 64 + rA;
  float bv[4];
  #pragma unroll
  for (int j = 0; j < 4; ++j) bv[j] = bias[col0 + j * 16];
  #pragma unroll
  for (int mi = 0; mi < 8; ++mi)
    #pragma unroll
    for (int j = 0; j < 4; ++j)
      #pragma unroll
      for (int q = 0; q < 4; ++q)
        C[(size_t)(row0 + mi * 16 + q) * JDIM + col0 + j * 16] = acc[mi][j][q] + bv[j];
}

extern "C" void kernel_launch(void* const* d_in, const int* in_sizes, int n_in,
                              void* d_out, int out_size, void* d_ws, size_t ws_size,
                              hipStream_t stream) {
  const float* x    = (const float*)d_in[0];
  const float* A    = (const float*)d_in[1];
  const float* Bb   = (const float*)d_in[2];
  const float* W    = (const float*)d_in[3];
  const float* bias = (const float*)d_in[4];
  float* out = (float*)d_out;

  char* ws = (char*)d_ws;
  // ws: XG 48M | WB 12M | Ahi 4M | Alo 4M | Af16 4M | cnt+tokidx (~8.1KB)
  unsigned short* XG  = (unsigned short*)ws;
  unsigned short* WB  = (unsigned short*)(ws + (size_t)48 * 1024 * 1024);
  unsigned short* Ahi = (unsigned short*)(ws + (size_t)60 * 1024 * 1024);
  unsigned short* Alo = (unsigned short*)(ws + (size_t)64 * 1024 * 1024);
  _Float16* Af16      = (_Float16*)(ws + (size_t)68 * 1024 * 1024);
  int* cnt            = (int*)(ws + (size_t)72 * 1024 * 1024);
  int* tokidx         = cnt + 16;
  // d_out scratch: lower 32MB vecs f32 [8192][1024]; upper 32MB Xf16 [8192][2048].
  float* vecs         = (float*)d_out;
  _Float16* Xf16      = (_Float16*)((char*)d_out + (size_t)32 * 1024 * 1024);

  cast_x_kernel<<<TOKENS, 256, 0, stream>>>(x, XG, Xf16);
  cast_a_kernel<<<KG, 256, 0, stream>>>(A, Af16, Ahi, Alo, cnt);
  cast2048_kernel<<<JDIM, 256, 0, stream>>>(W, WB, KTOT);
  cast_b_kernel<<<512, 256, 0, stream>>>(Bb, WB);

  // vecs = x @ A^T in fp16 (M=8192, N=1024, K=2048)
  gemm1f16_kernel<<<dim3(TOKENS / 128, KG / 128), 256, 0, stream>>>(Xf16, Af16, vecs);

  // routing + margin flagging
  route_kernel<<<TOKENS / 4, 256, 0, stream>>>(vecs, XG, cnt, tokidx);

  // exact recompute of flagged tokens' vec rows, then re-route them
  regemm_kernel<<<dim3(CAP / 128, KG / 128), 256, 0, stream>>>(
      x, Ahi, Alo, vecs, cnt, tokidx);
  route_fix_kernel<<<CAP / 4, 256, 0, stream>>>(vecs, XG, cnt, tokidx);

  // out = [Xb|G] @ [Wb|Bt]^T + bias   (M=8192, N=2048, K=3072), 8-phase 256² tile
  gemm2_8ph_kernel<<<256, 512, 0, stream>>>(XG, WB, out, bias);
}

// Round 7
// 240.895 us; speedup vs baseline: 1.1590x; 1.1590x over previous
//
#include <hip/hip_runtime.h>
#include <hip/hip_bf16.h>
#include <stdint.h>

// Shapes (fixed for this problem)
#define TOKENS 8192   // b*s = 4*2048
#define H 2048
#define JDIM 2048
#define NADAPT 64
#define RANK 16
#define KG 1024       // NADAPT*RANK
#define KTOT 3072     // H + KG
#define NT2 48        // gemm2 K-tiles = KTOT/64
#define NT1 64        // gemm1 K-tiles = H/32

typedef __bf16 v8bf __attribute__((ext_vector_type(8)));
typedef float v4f __attribute__((ext_vector_type(4)));
typedef unsigned short us8 __attribute__((ext_vector_type(8)));
typedef unsigned short us4 __attribute__((ext_vector_type(4)));

__device__ __forceinline__ unsigned short f2bf(float f) {
  union { __bf16 b; unsigned short u; } c; c.b = (__bf16)f; return c.u;
}
__device__ __forceinline__ float bf2f(unsigned short u) {
  union { unsigned int u; float f; } c; c.u = ((unsigned int)u) << 16; return c.f;
}

__device__ __forceinline__ us8 pack8(float4 a, float4 b) {
  us8 r;
  r[0]=f2bf(a.x); r[1]=f2bf(a.y); r[2]=f2bf(a.z); r[3]=f2bf(a.w);
  r[4]=f2bf(b.x); r[5]=f2bf(b.y); r[6]=f2bf(b.z); r[7]=f2bf(b.w);
  return r;
}

__device__ __forceinline__ void split8(float4 a, float4 b, us8& h, us8& l) {
  float v[8] = {a.x, a.y, a.z, a.w, b.x, b.y, b.z, b.w};
  #pragma unroll
  for (int i = 0; i < 8; ++i) {
    h[i] = f2bf(v[i]);
    l[i] = f2bf(v[i] - bf2f(h[i]));
  }
}

// x fp32 [8192][2048] -> hi bf16 into XG (stride KTOT), lo bf16 into XLO (stride 2048).
__global__ void cast_x_split_kernel(const float* __restrict__ x,
                                    unsigned short* __restrict__ XG,
                                    unsigned short* __restrict__ XLO) {
  int idx = blockIdx.x * 256 + threadIdx.x;
  int row = idx >> 8;
  int cg  = idx & 255;
  const float4* s = (const float4*)(x + ((size_t)row << 11) + ((size_t)cg << 3));
  float4 a = s[0], b = s[1];
  us8 h, l;
  split8(a, b, h, l);
  *(us8*)(XG  + (size_t)row * KTOT + ((size_t)cg << 3)) = h;
  *(us8*)(XLO + (size_t)row * H    + ((size_t)cg << 3)) = l;
}

// A fp32 [1024][2048] -> Ahi, Alo bf16 [1024][2048].
__global__ void cast_a_split_kernel(const float* __restrict__ A,
                                    unsigned short* __restrict__ Ahi,
                                    unsigned short* __restrict__ Alo) {
  int idx = blockIdx.x * 256 + threadIdx.x;
  int row = idx >> 8;
  int cg  = idx & 255;
  const float4* s = (const float4*)(A + ((size_t)row << 11) + ((size_t)cg << 3));
  float4 a = s[0], b = s[1];
  us8 h, l;
  split8(a, b, h, l);
  *(us8*)(Ahi + (size_t)row * H + ((size_t)cg << 3)) = h;
  *(us8*)(Alo + (size_t)row * H + ((size_t)cg << 3)) = l;
}

// fp32 [rows][2048] -> bf16 [rows][dstld] (fills cols 0..2047).
__global__ void cast2048_kernel(const float* __restrict__ src,
                                unsigned short* __restrict__ dst, int dstld) {
  int idx = blockIdx.x * 256 + threadIdx.x;
  int row = idx >> 8;
  int cg  = idx & 255;
  const float4* s = (const float4*)(src + ((size_t)row << 11) + ((size_t)cg << 3));
  float4 a = s[0], b = s[1];
  *(us8*)(dst + (size_t)row * dstld + ((size_t)cg << 3)) = pack8(a, b);
}

// B [64][2048][16] fp32 -> WB[j][2048 + a*16 + r] bf16. One thread per (a,j).
__global__ void cast_b_kernel(const float* __restrict__ Bsrc,
                              unsigned short* __restrict__ WB) {
  int idx = blockIdx.x * 256 + threadIdx.x;   // 131072 total
  int a = idx >> 11, j = idx & 2047;
  const float4* s = (const float4*)(Bsrc + (((size_t)a << 11) + j) * RANK);
  float4 f0 = s[0], f1 = s[1], f2 = s[2], f3 = s[3];
  us8* d = (us8*)(WB + (size_t)j * KTOT + H + a * RANK);
  d[0] = pack8(f0, f1);
  d[1] = pack8(f2, f3);
}

// Per token: arrows = sumsq over r, top-4 adapters, G row = routes*v.
__global__ void route_kernel(const float* __restrict__ vecs,
                             unsigned short* __restrict__ XG) {
  __shared__ float vsh[4][16];
  int wave = threadIdx.x >> 6, lane = threadIdx.x & 63;
  int t = blockIdx.x * 4 + wave;
  const float* vrow = vecs + (size_t)t * KG;
  const float4* vp = (const float4*)(vrow + lane * RANK);
  float4 q0 = vp[0], q1 = vp[1], q2 = vp[2], q3 = vp[3];
  float ss = q0.x*q0.x + q0.y*q0.y + q0.z*q0.z + q0.w*q0.w
           + q1.x*q1.x + q1.y*q1.y + q1.z*q1.z + q1.w*q1.w
           + q2.x*q2.x + q2.y*q2.y + q2.z*q2.z + q2.w*q2.w
           + q3.x*q3.x + q3.y*q3.y + q3.z*q3.z + q3.w*q3.w;
  float arr = ss;
  int sel[4];
  #pragma unroll
  for (int k = 0; k < 4; ++k) {
    float m = arr; int mi = lane;
    #pragma unroll
    for (int o = 32; o > 0; o >>= 1) {
      float om = __shfl_xor(m, o);
      int oi  = __shfl_xor(mi, o);
      if (om > m || (om == m && oi < mi)) { m = om; mi = oi; }
    }
    sel[k] = mi;                 // wave-uniform
    if (lane == mi) arr = -3.0e38f;
  }
  if (lane < 16) {
    float s = vrow[sel[0]*RANK + lane] + vrow[sel[1]*RANK + lane]
            + vrow[sel[2]*RANK + lane] + vrow[sel[3]*RANK + lane];
    vsh[wave][lane] = 0.0625f * s;
  }
  __syncthreads();
  bool on = (lane == sel[0]) | (lane == sel[1]) | (lane == sel[2]) | (lane == sel[3]);
  us8 lo, hi;
  #pragma unroll
  for (int r = 0; r < 8; ++r) lo[r] = on ? f2bf(vsh[wave][r])     : (unsigned short)0;
  #pragma unroll
  for (int r = 0; r < 8; ++r) hi[r] = on ? f2bf(vsh[wave][r + 8]) : (unsigned short)0;
  us8* d = (us8*)(XG + (size_t)t * KTOT + H + lane * RANK);
  d[0] = lo; d[1] = hi;
}

__device__ __forceinline__ void gload_lds16(const void* gsrc, void* ldst) {
  __builtin_amdgcn_global_load_lds(
      (const __attribute__((address_space(1))) unsigned int*)gsrc,
      (__attribute__((address_space(3))) unsigned int*)ldst, 16, 0, 0);
}

// Shared schedule helpers
#define BAR() asm volatile("s_waitcnt lgkmcnt(0)\n\ts_barrier" ::: "memory")
#define VM2() asm volatile("s_waitcnt vmcnt(2)" ::: "memory")
#define VM3() asm volatile("s_waitcnt vmcnt(3)" ::: "memory")
#define VM8() asm volatile("s_waitcnt vmcnt(8)" ::: "memory")
#define P1() __builtin_amdgcn_s_setprio(1)
#define P0() __builtin_amdgcn_s_setprio(0)

// ------------------------------------------------------------------
// GEMM1 (3-term split, 8-phase-class): vecs[8192,1024] =
//   Xhi@Ahi^T + Xhi@Alo^T + Xlo@Ahi^T (all bf16, fp32 acc).
// BM=256, BN=128, BK=32, 512 thr (8 waves 4Mx2N, per-wave 64x64).
// LDS per buf: XH 16K | XL 16K | AH 8K | AL 8K (=48K, x2 = 96K).
// 6 phases/K-tile, one 8KB stage-unit issued per phase for tile t+1;
// FIFO queue [XHu0,XHu1,AH,XLu0,XLu1,AL] -> vmcnt(2) end-p1, vmcnt(3) end-p5.
// Swizzle: 16B slot ^= (row>>1)&3 on stage-src and ds_read (both sides).
// ------------------------------------------------------------------
#define MM1(mi, xf, bv) do {                                                   \
  acc[mi][0] = __builtin_amdgcn_mfma_f32_16x16x32_bf16(xf, bv[0], acc[mi][0], 0, 0, 0); \
  acc[mi][1] = __builtin_amdgcn_mfma_f32_16x16x32_bf16(xf, bv[1], acc[mi][1], 0, 0, 0); \
  acc[mi][2] = __builtin_amdgcn_mfma_f32_16x16x32_bf16(xf, bv[2], acc[mi][2], 0, 0, 0); \
  acc[mi][3] = __builtin_amdgcn_mfma_f32_16x16x32_bf16(xf, bv[3], acc[mi][3], 0, 0, 0); \
} while (0)

#define LD1(off) (*(const v8bf*)(Lb + (off)))

#define S_XH1(b, kel) gload_lds16(XhB + (size_t)srow * KTOT + (kel) + scol, Lb + (b)*49152 + tid*16)
#define S_XH2(b, kel) gload_lds16(XhB + (size_t)(srow + 128) * KTOT + (kel) + scol, Lb + (b)*49152 + 8192 + tid*16)
#define S_XL1(b, kel) gload_lds16(XlB + (size_t)srow * H + (kel) + scol, Lb + (b)*49152 + 16384 + tid*16)
#define S_XL2(b, kel) gload_lds16(XlB + (size_t)(srow + 128) * H + (kel) + scol, Lb + (b)*49152 + 24576 + tid*16)
#define S_AH1(b, kel) gload_lds16(AhB + (size_t)srow * H + (kel) + scol, Lb + (b)*49152 + 32768 + tid*16)
#define S_AL1(b, kel) gload_lds16(AlB + (size_t)srow * H + (kel) + scol, Lb + (b)*49152 + 40960 + tid*16)

#define TILE1(c, n, kn) do {                                                   \
  /* p0: hi-hi mi 0,1 */                                                       \
  xh[0] = LD1((c)*49152 + abyte);                                              \
  xh[1] = LD1((c)*49152 + abyte + 1024);                                       \
  ah[0] = LD1((c)*49152 + 32768 + bbyte);                                      \
  ah[1] = LD1((c)*49152 + 32768 + bbyte + 1024);                               \
  ah[2] = LD1((c)*49152 + 32768 + bbyte + 2048);                               \
  ah[3] = LD1((c)*49152 + 32768 + bbyte + 3072);                               \
  S_XH1(n, kn);                                                                \
  BAR(); P1(); MM1(0, xh[0], ah); MM1(1, xh[1], ah); P0(); BAR();              \
  /* p1: hi-hi mi 2,3 */                                                       \
  xh[2] = LD1((c)*49152 + abyte + 2048);                                       \
  xh[3] = LD1((c)*49152 + abyte + 3072);                                       \
  S_XH2(n, kn);                                                                \
  BAR(); P1(); MM1(2, xh[2], ah); MM1(3, xh[3], ah); P0(); VM2(); BAR();       \
  /* p2: hi-lo mi 0,1 */                                                       \
  al[0] = LD1((c)*49152 + 40960 + bbyte);                                      \
  al[1] = LD1((c)*49152 + 40960 + bbyte + 1024);                               \
  al[2] = LD1((c)*49152 + 40960 + bbyte + 2048);                               \
  al[3] = LD1((c)*49152 + 40960 + bbyte + 3072);                               \
  S_AH1(n, kn);                                                                \
  BAR(); P1(); MM1(0, xh[0], al); MM1(1, xh[1], al); P0(); BAR();              \
  /* p3: hi-lo mi 2,3 */                                                       \
  S_XL1(n, kn);                                                                \
  BAR(); P1(); MM1(2, xh[2], al); MM1(3, xh[3], al); P0(); BAR();              \
  /* p4: lo-hi mi 0,1 */                                                       \
  xl[0] = LD1((c)*49152 + 16384 + abyte);                                      \
  xl[1] = LD1((c)*49152 + 16384 + abyte + 1024);                               \
  S_XL2(n, kn);                                                                \
  BAR(); P1(); MM1(0, xl[0], ah); MM1(1, xl[1], ah); P0(); BAR();              \
  /* p5: lo-hi mi 2,3 */                                                       \
  xl[2] = LD1((c)*49152 + 16384 + abyte + 2048);                               \
  xl[3] = LD1((c)*49152 + 16384 + abyte + 3072);                               \
  S_AL1(n, kn);                                                                \
  BAR(); P1(); MM1(2, xl[2], ah); MM1(3, xl[3], ah); P0(); VM3(); BAR();       \
} while (0)

__global__ __launch_bounds__(512, 1) void gemm1_8ph_kernel(
    const unsigned short* __restrict__ Xhi,   // stride KTOT (hi block of XG)
    const unsigned short* __restrict__ Xlo,   // stride H
    const unsigned short* __restrict__ Ahi,   // stride H
    const unsigned short* __restrict__ Alo,   // stride H
    float* __restrict__ C) {                  // [8192][1024]
  __shared__ char Ls[98304];                  // 96 KB
  char* Lb = Ls;
  const int tid = threadIdx.x;
  const int lane = tid & 63, wid = tid >> 6;
  const int wr = wid >> 1, wc = wid & 1;      // 4M x 2N waves, 64x64 each
  const int rA = lane & 15, grp = lane >> 4;
  const int grpx = (grp ^ ((rA >> 1) & 3)) << 4;

  const int bid = blockIdx.x;
  const int bn = bid & 7, bm = bid >> 3;      // XCD-pinned B panel (1MB, L2-fits)

  const unsigned short* XhB = Xhi + (size_t)(bm * 256) * KTOT;
  const unsigned short* XlB = Xlo + (size_t)(bm * 256) * H;
  const unsigned short* AhB = Ahi + (size_t)(bn * 128) * H;
  const unsigned short* AlB = Alo + (size_t)(bn * 128) * H;

  const int srow = tid >> 2;
  const int scol = ((tid & 3) ^ ((tid >> 3) & 3)) << 3;   // pre-swizzled src slot

  const int abyte = (wr * 64 + rA) * 64 + grpx;   // within XH/XL (+mi*1024)
  const int bbyte = (wc * 64 + rA) * 64 + grpx;   // within AH/AL (+nj*1024)

  v4f acc[4][4];
  #pragma unroll
  for (int i = 0; i < 4; ++i)
    #pragma unroll
    for (int j = 0; j < 4; ++j)
      acc[i][j] = (v4f){0.f, 0.f, 0.f, 0.f};
  v8bf xh[4], xl[4], ah[4], al[4];

  // prologue: stage tile 0, queue order [XHu0,XHu1,AH,XLu0,XLu1,AL]
  S_XH1(0, 0); S_XH2(0, 0); S_AH1(0, 0); S_XL1(0, 0); S_XL2(0, 0); S_AL1(0, 0);
  VM3(); BAR();

  #pragma unroll 1
  for (int t = 0; t < NT1; t += 2) {
    const int ka = (t + 1) * 32;                         // stage for tile t+1
    const int kb = (t + 2 < NT1 ? t + 2 : NT1 - 1) * 32; // stage for t+2 (clamped)
    TILE1(0, 1, ka);
    TILE1(1, 0, kb);
  }

  const int row0 = bm * 256 + wr * 64 + (grp << 2);
  const int col0 = bn * 128 + wc * 64 + rA;
  #pragma unroll
  for (int mi = 0; mi < 4; ++mi)
    #pragma unroll
    for (int j = 0; j < 4; ++j)
      #pragma unroll
      for (int q = 0; q < 4; ++q)
        C[(size_t)(row0 + mi * 16 + q) * KG + col0 + j * 16] = acc[mi][j][q];
}

// ------------------------------------------------------------------
// GEMM2: out[8192,2048] = XG[8192,3072]@WB[2048,3072]^T + bias. (unchanged)
// ------------------------------------------------------------------
#define STAGE(regionUS, panel, kelem) do {                                        \
  gload_lds16((panel) + aoff0 + (kelem), (char*)(regionUS) + tid * 16);           \
  gload_lds16((panel) + aoff1 + (kelem), (char*)(regionUS) + 8192 + tid * 16);    \
} while (0)

#define PHASE(mh, RAr, RBr, ISSUE, DOVM) do {                                     \
  if ((mh) == 0) {                                                                \
    _Pragma("unroll")                                                             \
    for (int j = 0; j < 4; ++j)                                                   \
      bfr[j] = *(const v8bf*)((const char*)(RBr) + bbyte + j * 1024);             \
  }                                                                               \
  _Pragma("unroll")                                                               \
  for (int i = 0; i < 4; ++i)                                                     \
    af[i] = *(const v8bf*)((const char*)(RAr) + abyte + ((mh)*4 + i) * 1024);     \
  ISSUE;                                                                          \
  BAR();                                                                          \
  P1();                                                                           \
  _Pragma("unroll")                                                               \
  for (int i = 0; i < 4; ++i)                                                     \
    _Pragma("unroll")                                                             \
    for (int j = 0; j < 4; ++j)                                                   \
      acc[(mh)*4 + i][j] = __builtin_amdgcn_mfma_f32_16x16x32_bf16(               \
          af[i], bfr[j], acc[(mh)*4 + i][j], 0, 0, 0);                            \
  P0();                                                                           \
  DOVM;                                                                           \
  BAR();                                                                          \
} while (0)

__global__ __launch_bounds__(512, 1) void gemm2_8ph_kernel(
    const unsigned short* __restrict__ Xg, const unsigned short* __restrict__ Wb,
    float* __restrict__ C, const float* __restrict__ bias) {
  __shared__ unsigned short lds[65536];   // 128 KB
  const int tid = threadIdx.x;
  const int lane = tid & 63, wid = tid >> 6;
  const int wr = wid >> 2, wc = wid & 3;
  const int rA = lane & 15, grp = lane >> 4;
  const int grpx = (grp ^ ((rA >> 1) & 3)) << 4;   // swizzled 16B slot (byte)

  const int bid = blockIdx.x;
  const int bn = bid & 7, bm = bid >> 3;           // each XCD owns one bn column

  const unsigned short* Ap = Xg + (size_t)(bm * 256) * KTOT;
  const unsigned short* Bp = Wb + (size_t)(bn * 256) * KTOT;

  const int srow = tid >> 2;
  const int scol = ((tid & 3) ^ ((tid >> 3) & 3)) << 3;
  const size_t aoff0 = (size_t)srow * KTOT + scol;
  const size_t aoff1 = (size_t)(srow + 128) * KTOT + scol;

  unsigned short* A0k0 = lds;
  unsigned short* A0k1 = lds + 8192;
  unsigned short* B0k0 = lds + 16384;
  unsigned short* B0k1 = lds + 24576;
  unsigned short* A1k0 = lds + 32768;
  unsigned short* A1k1 = lds + 40960;
  unsigned short* B1k0 = lds + 49152;
  unsigned short* B1k1 = lds + 57344;

  const int abyte = (wr * 128 + rA) * 64 + grpx;
  const int bbyte = (wc * 64 + rA) * 64 + grpx;

  v4f acc[8][4];
  #pragma unroll
  for (int i = 0; i < 8; ++i)
    #pragma unroll
    for (int j = 0; j < 4; ++j)
      acc[i][j] = (v4f){0.f, 0.f, 0.f, 0.f};
  v8bf af[4], bfr[4];

  STAGE(A0k0, Ap, 0);
  STAGE(B0k0, Bp, 0);
  STAGE(A0k1, Ap, 32);
  STAGE(B0k1, Bp, 32);
  STAGE(A1k0, Ap, 64);
  STAGE(B1k0, Bp, 64);
  VM8();
  BAR();

  #pragma unroll 1
  for (int t = 0; t < NT2; t += 2) {
    const int k1a = (t + 1) * 64 + 32;
    const int k0a = (t + 2 < NT2 ? t + 2 : NT2 - 1) * 64;
    const int k1b = (t + 2 < NT2 ? t + 2 : NT2 - 1) * 64 + 32;
    const int k0b = (t + 3 < NT2 ? t + 3 : NT2 - 1) * 64;
    PHASE(0, A0k0, B0k0, STAGE(A1k1, Ap, k1a), ((void)0));
    PHASE(1, A0k0, B0k0, STAGE(B1k1, Bp, k1a), VM8());
    PHASE(0, A0k1, B0k1, STAGE(A0k0, Ap, k0a), ((void)0));
    PHASE(1, A0k1, B0k1, STAGE(B0k0, Bp, k0a), VM8());
    PHASE(0, A1k0, B1k0, STAGE(A0k1, Ap, k1b), ((void)0));
    PHASE(1, A1k0, B1k0, STAGE(B0k1, Bp, k1b), VM8());
    PHASE(0, A1k1, B1k1, STAGE(A1k0, Ap, k0b), ((void)0));
    PHASE(1, A1k1, B1k1, STAGE(B1k0, Bp, k0b), VM8());
  }

  const int row0 = bm * 256 + wr * 128 + (grp << 2);
  const int col0 = bn * 256 + wc * 64 + rA;
  float bv[4];
  #pragma unroll
  for (int j = 0; j < 4; ++j) bv[j] = bias[col0 + j * 16];
  #pragma unroll
  for (int mi = 0; mi < 8; ++mi)
    #pragma unroll
    for (int j = 0; j < 4; ++j)
      #pragma unroll
      for (int q = 0; q < 4; ++q)
        C[(size_t)(row0 + mi * 16 + q) * JDIM + col0 + j * 16] = acc[mi][j][q] + bv[j];
}

extern "C" void kernel_launch(void* const* d_in, const int* in_sizes, int n_in,
                              void* d_out, int out_size, void* d_ws, size_t ws_size,
                              hipStream_t stream) {
  const float* x    = (const float*)d_in[0];
  const float* A    = (const float*)d_in[1];
  const float* Bb   = (const float*)d_in[2];
  const float* W    = (const float*)d_in[3];
  const float* bias = (const float*)d_in[4];
  float* out = (float*)d_out;

  char* ws = (char*)d_ws;
  // ws layout: XG bf16 [8192][3072] (48M) | WB bf16 [2048][3072] (12M) |
  //            Ahi bf16 [1024][2048] (4M) | Alo bf16 [1024][2048] (4M)   = 68M
  unsigned short* XG  = (unsigned short*)ws;
  unsigned short* WB  = (unsigned short*)(ws + (size_t)48 * 1024 * 1024);
  unsigned short* Ahi = (unsigned short*)(ws + (size_t)60 * 1024 * 1024);
  unsigned short* Alo = (unsigned short*)(ws + (size_t)64 * 1024 * 1024);
  // d_out doubles as pre-gemm2 scratch: lower 32MB vecs f32, upper 32MB x_lo bf16.
  float* vecs         = (float*)d_out;
  unsigned short* XLO = (unsigned short*)((char*)d_out + (size_t)32 * 1024 * 1024);

  cast_x_split_kernel<<<TOKENS, 256, 0, stream>>>(x, XG, XLO);
  cast_a_split_kernel<<<KG, 256, 0, stream>>>(A, Ahi, Alo);
  cast2048_kernel<<<JDIM, 256, 0, stream>>>(W, WB, KTOT);
  cast_b_kernel<<<512, 256, 0, stream>>>(Bb, WB);

  // vecs = x @ A^T in near-fp32 (3-term bf16 split), 8-phase-class schedule
  gemm1_8ph_kernel<<<256, 512, 0, stream>>>(XG, XLO, Ahi, Alo, vecs);

  // routing -> G block of XG
  route_kernel<<<TOKENS / 4, 256, 0, stream>>>(vecs, XG);

  // out = [Xb|G] @ [Wb|Bt]^T + bias   (M=8192, N=2048, K=3072), 8-phase 256² tile
  gemm2_8ph_kernel<<<256, 512, 0, stream>>>(XG, WB, out, bias);
}

// Round 8
// 224.090 us; speedup vs baseline: 1.2459x; 1.0750x over previous
//
#include <hip/hip_runtime.h>
#include <hip/hip_bf16.h>
#include <stdint.h>

// Shapes (fixed for this problem)
#define TOKENS 8192   // b*s = 4*2048
#define H 2048
#define JDIM 2048
#define NADAPT 64
#define RANK 16
#define KG 1024       // NADAPT*RANK
#define KTOT 3072     // H + KG
#define NT2 48        // gemm2 K-tiles = KTOT/64
#define NT1 64        // gemm1 K-tiles = H/32

typedef __bf16 v8bf __attribute__((ext_vector_type(8)));
typedef float v4f __attribute__((ext_vector_type(4)));
typedef unsigned short us8 __attribute__((ext_vector_type(8)));
typedef unsigned short us4 __attribute__((ext_vector_type(4)));

__device__ __forceinline__ unsigned short f2bf(float f) {
  union { __bf16 b; unsigned short u; } c; c.b = (__bf16)f; return c.u;
}
__device__ __forceinline__ float bf2f(unsigned short u) {
  union { unsigned int u; float f; } c; c.u = ((unsigned int)u) << 16; return c.f;
}

__device__ __forceinline__ us8 pack8(float4 a, float4 b) {
  us8 r;
  r[0]=f2bf(a.x); r[1]=f2bf(a.y); r[2]=f2bf(a.z); r[3]=f2bf(a.w);
  r[4]=f2bf(b.x); r[5]=f2bf(b.y); r[6]=f2bf(b.z); r[7]=f2bf(b.w);
  return r;
}

__device__ __forceinline__ void split8(float4 a, float4 b, us8& h, us8& l) {
  float v[8] = {a.x, a.y, a.z, a.w, b.x, b.y, b.z, b.w};
  #pragma unroll
  for (int i = 0; i < 8; ++i) {
    h[i] = f2bf(v[i]);
    l[i] = f2bf(v[i] - bf2f(h[i]));
  }
}

// x fp32 [8192][2048] -> hi bf16 into XG (stride KTOT), lo bf16 into XLO (stride 2048).
__global__ void cast_x_split_kernel(const float* __restrict__ x,
                                    unsigned short* __restrict__ XG,
                                    unsigned short* __restrict__ XLO) {
  int idx = blockIdx.x * 256 + threadIdx.x;
  int row = idx >> 8;
  int cg  = idx & 255;
  const float4* s = (const float4*)(x + ((size_t)row << 11) + ((size_t)cg << 3));
  float4 a = s[0], b = s[1];
  us8 h, l;
  split8(a, b, h, l);
  *(us8*)(XG  + (size_t)row * KTOT + ((size_t)cg << 3)) = h;
  *(us8*)(XLO + (size_t)row * H    + ((size_t)cg << 3)) = l;
}

// A fp32 [1024][2048] -> Ahi, Alo bf16 [1024][2048].
__global__ void cast_a_split_kernel(const float* __restrict__ A,
                                    unsigned short* __restrict__ Ahi,
                                    unsigned short* __restrict__ Alo) {
  int idx = blockIdx.x * 256 + threadIdx.x;
  int row = idx >> 8;
  int cg  = idx & 255;
  const float4* s = (const float4*)(A + ((size_t)row << 11) + ((size_t)cg << 3));
  float4 a = s[0], b = s[1];
  us8 h, l;
  split8(a, b, h, l);
  *(us8*)(Ahi + (size_t)row * H + ((size_t)cg << 3)) = h;
  *(us8*)(Alo + (size_t)row * H + ((size_t)cg << 3)) = l;
}

// fp32 [rows][2048] -> bf16 [rows][dstld] (fills cols 0..2047).
__global__ void cast2048_kernel(const float* __restrict__ src,
                                unsigned short* __restrict__ dst, int dstld) {
  int idx = blockIdx.x * 256 + threadIdx.x;
  int row = idx >> 8;
  int cg  = idx & 255;
  const float4* s = (const float4*)(src + ((size_t)row << 11) + ((size_t)cg << 3));
  float4 a = s[0], b = s[1];
  *(us8*)(dst + (size_t)row * dstld + ((size_t)cg << 3)) = pack8(a, b);
}

// B [64][2048][16] fp32 -> WB[j][2048 + a*16 + r] bf16. One thread per (a,j).
__global__ void cast_b_kernel(const float* __restrict__ Bsrc,
                              unsigned short* __restrict__ WB) {
  int idx = blockIdx.x * 256 + threadIdx.x;   // 131072 total
  int a = idx >> 11, j = idx & 2047;
  const float4* s = (const float4*)(Bsrc + (((size_t)a << 11) + j) * RANK);
  float4 f0 = s[0], f1 = s[1], f2 = s[2], f3 = s[3];
  us8* d = (us8*)(WB + (size_t)j * KTOT + H + a * RANK);
  d[0] = pack8(f0, f1);
  d[1] = pack8(f2, f3);
}

// Per token: arrows = sumsq over r, top-4 adapters, G row = routes*v.
__global__ void route_kernel(const float* __restrict__ vecs,
                             unsigned short* __restrict__ XG) {
  __shared__ float vsh[4][16];
  int wave = threadIdx.x >> 6, lane = threadIdx.x & 63;
  int t = blockIdx.x * 4 + wave;
  const float* vrow = vecs + (size_t)t * KG;
  const float4* vp = (const float4*)(vrow + lane * RANK);
  float4 q0 = vp[0], q1 = vp[1], q2 = vp[2], q3 = vp[3];
  float ss = q0.x*q0.x + q0.y*q0.y + q0.z*q0.z + q0.w*q0.w
           + q1.x*q1.x + q1.y*q1.y + q1.z*q1.z + q1.w*q1.w
           + q2.x*q2.x + q2.y*q2.y + q2.z*q2.z + q2.w*q2.w
           + q3.x*q3.x + q3.y*q3.y + q3.z*q3.z + q3.w*q3.w;
  float arr = ss;
  int sel[4];
  #pragma unroll
  for (int k = 0; k < 4; ++k) {
    float m = arr; int mi = lane;
    #pragma unroll
    for (int o = 32; o > 0; o >>= 1) {
      float om = __shfl_xor(m, o);
      int oi  = __shfl_xor(mi, o);
      if (om > m || (om == m && oi < mi)) { m = om; mi = oi; }
    }
    sel[k] = mi;                 // wave-uniform
    if (lane == mi) arr = -3.0e38f;
  }
  if (lane < 16) {
    float s = vrow[sel[0]*RANK + lane] + vrow[sel[1]*RANK + lane]
            + vrow[sel[2]*RANK + lane] + vrow[sel[3]*RANK + lane];
    vsh[wave][lane] = 0.0625f * s;
  }
  __syncthreads();
  bool on = (lane == sel[0]) | (lane == sel[1]) | (lane == sel[2]) | (lane == sel[3]);
  us8 lo, hi;
  #pragma unroll
  for (int r = 0; r < 8; ++r) lo[r] = on ? f2bf(vsh[wave][r])     : (unsigned short)0;
  #pragma unroll
  for (int r = 0; r < 8; ++r) hi[r] = on ? f2bf(vsh[wave][r + 8]) : (unsigned short)0;
  us8* d = (us8*)(XG + (size_t)t * KTOT + H + lane * RANK);
  d[0] = lo; d[1] = hi;
}

__device__ __forceinline__ void gload_lds16(const void* gsrc, void* ldst) {
  __builtin_amdgcn_global_load_lds(
      (const __attribute__((address_space(1))) unsigned int*)gsrc,
      (__attribute__((address_space(3))) unsigned int*)ldst, 16, 0, 0);
}

// Shared schedule helpers
#define BAR() asm volatile("s_waitcnt lgkmcnt(0)\n\ts_barrier" ::: "memory")
#define VM2() asm volatile("s_waitcnt vmcnt(2)" ::: "memory")
#define VM3() asm volatile("s_waitcnt vmcnt(3)" ::: "memory")
#define VM8() asm volatile("s_waitcnt vmcnt(8)" ::: "memory")
#define P1() __builtin_amdgcn_s_setprio(1)
#define P0() __builtin_amdgcn_s_setprio(0)

// ------------------------------------------------------------------
// GEMM1 (3-term split): vecs[8192,1024] = Xhi@Ahi^T + Xhi@Alo^T + Xlo@Ahi^T.
// BM=256, BN=128, BK=32, 512 thr (8 waves 4Mx2N, per-wave 64x64).
// LDS per buf: XH 16K | XL 16K | AH 8K | AL 8K (=48K, x2 = 96K).
// 3 phases/K-tile, 16 MFMA per phase (barrier per 8 MFMA), 2 stage-units/phase.
// FIFO [XH1,XH2|AH,XL1|XL2,AL] -> VM2 end-p0, VM3 end-p2, never 0.
// Swizzle: 16B slot ^= (row>>1)&3 on stage-src and ds_read (both sides).
// XCD map: bm-pinned (per-XCD X working set 8MB vs 64MB bn-pinned).
// ------------------------------------------------------------------
#define MM1(mi, xf, bv) do {                                                   \
  acc[mi][0] = __builtin_amdgcn_mfma_f32_16x16x32_bf16(xf, bv[0], acc[mi][0], 0, 0, 0); \
  acc[mi][1] = __builtin_amdgcn_mfma_f32_16x16x32_bf16(xf, bv[1], acc[mi][1], 0, 0, 0); \
  acc[mi][2] = __builtin_amdgcn_mfma_f32_16x16x32_bf16(xf, bv[2], acc[mi][2], 0, 0, 0); \
  acc[mi][3] = __builtin_amdgcn_mfma_f32_16x16x32_bf16(xf, bv[3], acc[mi][3], 0, 0, 0); \
} while (0)

#define LD1(off) (*(const v8bf*)(Lb + (off)))

#define S_XH1(b, kel) gload_lds16(XhB + (size_t)srow * KTOT + (kel) + scol, Lb + (b)*49152 + tid*16)
#define S_XH2(b, kel) gload_lds16(XhB + (size_t)(srow + 128) * KTOT + (kel) + scol, Lb + (b)*49152 + 8192 + tid*16)
#define S_XL1(b, kel) gload_lds16(XlB + (size_t)srow * H + (kel) + scol, Lb + (b)*49152 + 16384 + tid*16)
#define S_XL2(b, kel) gload_lds16(XlB + (size_t)(srow + 128) * H + (kel) + scol, Lb + (b)*49152 + 24576 + tid*16)
#define S_AH1(b, kel) gload_lds16(AhB + (size_t)srow * H + (kel) + scol, Lb + (b)*49152 + 32768 + tid*16)
#define S_AL1(b, kel) gload_lds16(AlB + (size_t)srow * H + (kel) + scol, Lb + (b)*49152 + 40960 + tid*16)

#define TILE1(c, n, kn) do {                                                   \
  /* p0: hi*hi, mi 0..3 */                                                     \
  xh[0] = LD1((c)*49152 + abyte);                                              \
  xh[1] = LD1((c)*49152 + abyte + 1024);                                       \
  xh[2] = LD1((c)*49152 + abyte + 2048);                                       \
  xh[3] = LD1((c)*49152 + abyte + 3072);                                       \
  ah[0] = LD1((c)*49152 + 32768 + bbyte);                                      \
  ah[1] = LD1((c)*49152 + 32768 + bbyte + 1024);                               \
  ah[2] = LD1((c)*49152 + 32768 + bbyte + 2048);                               \
  ah[3] = LD1((c)*49152 + 32768 + bbyte + 3072);                               \
  S_XH1(n, kn); S_XH2(n, kn);                                                  \
  BAR(); P1(); MM1(0, xh[0], ah); MM1(1, xh[1], ah);                           \
               MM1(2, xh[2], ah); MM1(3, xh[3], ah); P0(); VM2(); BAR();       \
  /* p1: hi*lo, mi 0..3 */                                                     \
  al[0] = LD1((c)*49152 + 40960 + bbyte);                                      \
  al[1] = LD1((c)*49152 + 40960 + bbyte + 1024);                               \
  al[2] = LD1((c)*49152 + 40960 + bbyte + 2048);                               \
  al[3] = LD1((c)*49152 + 40960 + bbyte + 3072);                               \
  S_AH1(n, kn); S_XL1(n, kn);                                                  \
  BAR(); P1(); MM1(0, xh[0], al); MM1(1, xh[1], al);                           \
               MM1(2, xh[2], al); MM1(3, xh[3], al); P0(); BAR();              \
  /* p2: lo*hi, mi 0..3 */                                                     \
  xl[0] = LD1((c)*49152 + 16384 + abyte);                                      \
  xl[1] = LD1((c)*49152 + 16384 + abyte + 1024);                               \
  xl[2] = LD1((c)*49152 + 16384 + abyte + 2048);                               \
  xl[3] = LD1((c)*49152 + 16384 + abyte + 3072);                               \
  S_XL2(n, kn); S_AL1(n, kn);                                                  \
  BAR(); P1(); MM1(0, xl[0], ah); MM1(1, xl[1], ah);                           \
               MM1(2, xl[2], ah); MM1(3, xl[3], ah); P0(); VM3(); BAR();       \
} while (0)

__global__ __launch_bounds__(512, 1) void gemm1_8ph_kernel(
    const unsigned short* __restrict__ Xhi,   // stride KTOT (hi block of XG)
    const unsigned short* __restrict__ Xlo,   // stride H
    const unsigned short* __restrict__ Ahi,   // stride H
    const unsigned short* __restrict__ Alo,   // stride H
    float* __restrict__ C) {                  // [8192][1024]
  __shared__ char Ls[98304];                  // 96 KB
  char* Lb = Ls;
  const int tid = threadIdx.x;
  const int lane = tid & 63, wid = tid >> 6;
  const int wr = wid >> 1, wc = wid & 1;      // 4M x 2N waves, 64x64 each
  const int rA = lane & 15, grp = lane >> 4;
  const int grpx = (grp ^ ((rA >> 1) & 3)) << 4;

  const int bid = blockIdx.x;
  const int g = bid & 7, r = bid >> 3;
  const int bm = g * 4 + (r & 3), bn = r >> 2;  // bm-pinned per XCD

  const unsigned short* XhB = Xhi + (size_t)(bm * 256) * KTOT;
  const unsigned short* XlB = Xlo + (size_t)(bm * 256) * H;
  const unsigned short* AhB = Ahi + (size_t)(bn * 128) * H;
  const unsigned short* AlB = Alo + (size_t)(bn * 128) * H;

  const int srow = tid >> 2;
  const int scol = ((tid & 3) ^ ((tid >> 3) & 3)) << 3;   // pre-swizzled src slot

  const int abyte = (wr * 64 + rA) * 64 + grpx;   // within XH/XL (+mi*1024)
  const int bbyte = (wc * 64 + rA) * 64 + grpx;   // within AH/AL (+nj*1024)

  v4f acc[4][4];
  #pragma unroll
  for (int i = 0; i < 4; ++i)
    #pragma unroll
    for (int j = 0; j < 4; ++j)
      acc[i][j] = (v4f){0.f, 0.f, 0.f, 0.f};
  v8bf xh[4], xl[4], ah[4], al[4];

  // prologue: stage tile 0, queue order [XH1,XH2,AH,XL1,XL2,AL]
  S_XH1(0, 0); S_XH2(0, 0); S_AH1(0, 0); S_XL1(0, 0); S_XL2(0, 0); S_AL1(0, 0);
  VM3(); BAR();

  #pragma unroll 1
  for (int t = 0; t < NT1; t += 2) {
    const int ka = (t + 1) * 32;                         // stage for tile t+1
    const int kb = (t + 2 < NT1 ? t + 2 : NT1 - 1) * 32; // stage for t+2 (clamped)
    TILE1(0, 1, ka);
    TILE1(1, 0, kb);
  }

  const int row0 = bm * 256 + wr * 64 + (grp << 2);
  const int col0 = bn * 128 + wc * 64 + rA;
  #pragma unroll
  for (int mi = 0; mi < 4; ++mi)
    #pragma unroll
    for (int j = 0; j < 4; ++j)
      #pragma unroll
      for (int q = 0; q < 4; ++q)
        C[(size_t)(row0 + mi * 16 + q) * KG + col0 + j * 16] = acc[mi][j][q];
}

// ------------------------------------------------------------------
// GEMM2: out[8192,2048] = XG[8192,3072]@WB[2048,3072]^T + bias. (unchanged)
// ------------------------------------------------------------------
#define STAGE(regionUS, panel, kelem) do {                                        \
  gload_lds16((panel) + aoff0 + (kelem), (char*)(regionUS) + tid * 16);           \
  gload_lds16((panel) + aoff1 + (kelem), (char*)(regionUS) + 8192 + tid * 16);    \
} while (0)

#define PHASE(mh, RAr, RBr, ISSUE, DOVM) do {                                     \
  if ((mh) == 0) {                                                                \
    _Pragma("unroll")                                                             \
    for (int j = 0; j < 4; ++j)                                                   \
      bfr[j] = *(const v8bf*)((const char*)(RBr) + bbyte + j * 1024);             \
  }                                                                               \
  _Pragma("unroll")                                                               \
  for (int i = 0; i < 4; ++i)                                                     \
    af[i] = *(const v8bf*)((const char*)(RAr) + abyte + ((mh)*4 + i) * 1024);     \
  ISSUE;                                                                          \
  BAR();                                                                          \
  P1();                                                                           \
  _Pragma("unroll")                                                               \
  for (int i = 0; i < 4; ++i)                                                     \
    _Pragma("unroll")                                                             \
    for (int j = 0; j < 4; ++j)                                                   \
      acc[(mh)*4 + i][j] = __builtin_amdgcn_mfma_f32_16x16x32_bf16(               \
          af[i], bfr[j], acc[(mh)*4 + i][j], 0, 0, 0);                            \
  P0();                                                                           \
  DOVM;                                                                           \
  BAR();                                                                          \
} while (0)

__global__ __launch_bounds__(512, 1) void gemm2_8ph_kernel(
    const unsigned short* __restrict__ Xg, const unsigned short* __restrict__ Wb,
    float* __restrict__ C, const float* __restrict__ bias) {
  __shared__ unsigned short lds[65536];   // 128 KB
  const int tid = threadIdx.x;
  const int lane = tid & 63, wid = tid >> 6;
  const int wr = wid >> 2, wc = wid & 3;
  const int rA = lane & 15, grp = lane >> 4;
  const int grpx = (grp ^ ((rA >> 1) & 3)) << 4;   // swizzled 16B slot (byte)

  const int bid = blockIdx.x;
  const int bn = bid & 7, bm = bid >> 3;           // each XCD owns one bn column

  const unsigned short* Ap = Xg + (size_t)(bm * 256) * KTOT;
  const unsigned short* Bp = Wb + (size_t)(bn * 256) * KTOT;

  const int srow = tid >> 2;
  const int scol = ((tid & 3) ^ ((tid >> 3) & 3)) << 3;
  const size_t aoff0 = (size_t)srow * KTOT + scol;
  const size_t aoff1 = (size_t)(srow + 128) * KTOT + scol;

  unsigned short* A0k0 = lds;
  unsigned short* A0k1 = lds + 8192;
  unsigned short* B0k0 = lds + 16384;
  unsigned short* B0k1 = lds + 24576;
  unsigned short* A1k0 = lds + 32768;
  unsigned short* A1k1 = lds + 40960;
  unsigned short* B1k0 = lds + 49152;
  unsigned short* B1k1 = lds + 57344;

  const int abyte = (wr * 128 + rA) * 64 + grpx;
  const int bbyte = (wc * 64 + rA) * 64 + grpx;

  v4f acc[8][4];
  #pragma unroll
  for (int i = 0; i < 8; ++i)
    #pragma unroll
    for (int j = 0; j < 4; ++j)
      acc[i][j] = (v4f){0.f, 0.f, 0.f, 0.f};
  v8bf af[4], bfr[4];

  STAGE(A0k0, Ap, 0);
  STAGE(B0k0, Bp, 0);
  STAGE(A0k1, Ap, 32);
  STAGE(B0k1, Bp, 32);
  STAGE(A1k0, Ap, 64);
  STAGE(B1k0, Bp, 64);
  VM8();
  BAR();

  #pragma unroll 1
  for (int t = 0; t < NT2; t += 2) {
    const int k1a = (t + 1) * 64 + 32;
    const int k0a = (t + 2 < NT2 ? t + 2 : NT2 - 1) * 64;
    const int k1b = (t + 2 < NT2 ? t + 2 : NT2 - 1) * 64 + 32;
    const int k0b = (t + 3 < NT2 ? t + 3 : NT2 - 1) * 64;
    PHASE(0, A0k0, B0k0, STAGE(A1k1, Ap, k1a), ((void)0));
    PHASE(1, A0k0, B0k0, STAGE(B1k1, Bp, k1a), VM8());
    PHASE(0, A0k1, B0k1, STAGE(A0k0, Ap, k0a), ((void)0));
    PHASE(1, A0k1, B0k1, STAGE(B0k0, Bp, k0a), VM8());
    PHASE(0, A1k0, B1k0, STAGE(A0k1, Ap, k1b), ((void)0));
    PHASE(1, A1k0, B1k0, STAGE(B0k1, Bp, k1b), VM8());
    PHASE(0, A1k1, B1k1, STAGE(A1k0, Ap, k0b), ((void)0));
    PHASE(1, A1k1, B1k1, STAGE(B1k0, Bp, k0b), VM8());
  }

  const int row0 = bm * 256 + wr * 128 + (grp << 2);
  const int col0 = bn * 256 + wc * 64 + rA;
  float bv[4];
  #pragma unroll
  for (int j = 0; j < 4; ++j) bv[j] = bias[col0 + j * 16];
  #pragma unroll
  for (int mi = 0; mi < 8; ++mi)
    #pragma unroll
    for (int j = 0; j < 4; ++j)
      #pragma unroll
      for (int q = 0; q < 4; ++q)
        C[(size_t)(row0 + mi * 16 + q) * JDIM + col0 + j * 16] = acc[mi][j][q] + bv[j];
}

extern "C" void kernel_launch(void* const* d_in, const int* in_sizes, int n_in,
                              void* d_out, int out_size, void* d_ws, size_t ws_size,
                              hipStream_t stream) {
  const float* x    = (const float*)d_in[0];
  const float* A    = (const float*)d_in[1];
  const float* Bb   = (const float*)d_in[2];
  const float* W    = (const float*)d_in[3];
  const float* bias = (const float*)d_in[4];
  float* out = (float*)d_out;

  char* ws = (char*)d_ws;
  // ws layout: XG bf16 [8192][3072] (48M) | WB bf16 [2048][3072] (12M) |
  //            Ahi bf16 [1024][2048] (4M) | Alo bf16 [1024][2048] (4M)   = 68M
  unsigned short* XG  = (unsigned short*)ws;
  unsigned short* WB  = (unsigned short*)(ws + (size_t)48 * 1024 * 1024);
  unsigned short* Ahi = (unsigned short*)(ws + (size_t)60 * 1024 * 1024);
  unsigned short* Alo = (unsigned short*)(ws + (size_t)64 * 1024 * 1024);
  // d_out doubles as pre-gemm2 scratch: lower 32MB vecs f32, upper 32MB x_lo bf16.
  float* vecs         = (float*)d_out;
  unsigned short* XLO = (unsigned short*)((char*)d_out + (size_t)32 * 1024 * 1024);

  cast_x_split_kernel<<<TOKENS, 256, 0, stream>>>(x, XG, XLO);
  cast_a_split_kernel<<<KG, 256, 0, stream>>>(A, Ahi, Alo);
  cast2048_kernel<<<JDIM, 256, 0, stream>>>(W, WB, KTOT);
  cast_b_kernel<<<512, 256, 0, stream>>>(Bb, WB);

  // vecs = x @ A^T in near-fp32 (3-term bf16 split), 3-phase counted-vmcnt schedule
  gemm1_8ph_kernel<<<256, 512, 0, stream>>>(XG, XLO, Ahi, Alo, vecs);

  // routing -> G block of XG
  route_kernel<<<TOKENS / 4, 256, 0, stream>>>(vecs, XG);

  // out = [Xb|G] @ [Wb|Bt]^T + bias   (M=8192, N=2048, K=3072), 8-phase 256² tile
  gemm2_8ph_kernel<<<256, 512, 0, stream>>>(XG, WB, out, bias);
}

// Round 9
// 222.015 us; speedup vs baseline: 1.2575x; 1.0093x over previous
//
#include <hip/hip_runtime.h>
#include <hip/hip_bf16.h>
#include <stdint.h>

// Shapes (fixed for this problem)
#define TOKENS 8192   // b*s = 4*2048
#define H 2048
#define JDIM 2048
#define NADAPT 64
#define RANK 16
#define KG 1024       // NADAPT*RANK
#define KTOT 3072     // H + KG
#define NT2 48        // gemm2 K-tiles = KTOT/64
#define NT1 64        // gemm1 K-tiles = H/32

typedef __bf16 v8bf __attribute__((ext_vector_type(8)));
typedef float v4f __attribute__((ext_vector_type(4)));
typedef unsigned short us8 __attribute__((ext_vector_type(8)));
typedef unsigned short us4 __attribute__((ext_vector_type(4)));

__device__ __forceinline__ unsigned short f2bf(float f) {
  union { __bf16 b; unsigned short u; } c; c.b = (__bf16)f; return c.u;
}
__device__ __forceinline__ float bf2f(unsigned short u) {
  union { unsigned int u; float f; } c; c.u = ((unsigned int)u) << 16; return c.f;
}

__device__ __forceinline__ us8 pack8(float4 a, float4 b) {
  us8 r;
  r[0]=f2bf(a.x); r[1]=f2bf(a.y); r[2]=f2bf(a.z); r[3]=f2bf(a.w);
  r[4]=f2bf(b.x); r[5]=f2bf(b.y); r[6]=f2bf(b.z); r[7]=f2bf(b.w);
  return r;
}

__device__ __forceinline__ void split8(float4 a, float4 b, us8& h, us8& l) {
  float v[8] = {a.x, a.y, a.z, a.w, b.x, b.y, b.z, b.w};
  #pragma unroll
  for (int i = 0; i < 8; ++i) {
    h[i] = f2bf(v[i]);
    l[i] = f2bf(v[i] - bf2f(h[i]));
  }
}

// x fp32 [8192][2048] -> hi bf16 into XG (stride KTOT), lo bf16 into XLO (stride 2048).
__global__ void cast_x_split_kernel(const float* __restrict__ x,
                                    unsigned short* __restrict__ XG,
                                    unsigned short* __restrict__ XLO) {
  int idx = blockIdx.x * 256 + threadIdx.x;
  int row = idx >> 8;
  int cg  = idx & 255;
  const float4* s = (const float4*)(x + ((size_t)row << 11) + ((size_t)cg << 3));
  float4 a = s[0], b = s[1];
  us8 h, l;
  split8(a, b, h, l);
  *(us8*)(XG  + (size_t)row * KTOT + ((size_t)cg << 3)) = h;
  *(us8*)(XLO + (size_t)row * H    + ((size_t)cg << 3)) = l;
}

// A fp32 [1024][2048] -> Ahi, Alo bf16 [1024][2048].
__global__ void cast_a_split_kernel(const float* __restrict__ A,
                                    unsigned short* __restrict__ Ahi,
                                    unsigned short* __restrict__ Alo) {
  int idx = blockIdx.x * 256 + threadIdx.x;
  int row = idx >> 8;
  int cg  = idx & 255;
  const float4* s = (const float4*)(A + ((size_t)row << 11) + ((size_t)cg << 3));
  float4 a = s[0], b = s[1];
  us8 h, l;
  split8(a, b, h, l);
  *(us8*)(Ahi + (size_t)row * H + ((size_t)cg << 3)) = h;
  *(us8*)(Alo + (size_t)row * H + ((size_t)cg << 3)) = l;
}

// fp32 [rows][2048] -> bf16 [rows][dstld] (fills cols 0..2047).
__global__ void cast2048_kernel(const float* __restrict__ src,
                                unsigned short* __restrict__ dst, int dstld) {
  int idx = blockIdx.x * 256 + threadIdx.x;
  int row = idx >> 8;
  int cg  = idx & 255;
  const float4* s = (const float4*)(src + ((size_t)row << 11) + ((size_t)cg << 3));
  float4 a = s[0], b = s[1];
  *(us8*)(dst + (size_t)row * dstld + ((size_t)cg << 3)) = pack8(a, b);
}

// B [64][2048][16] fp32 -> WB[j][2048 + a*16 + r] bf16. One thread per (a,j).
__global__ void cast_b_kernel(const float* __restrict__ Bsrc,
                              unsigned short* __restrict__ WB) {
  int idx = blockIdx.x * 256 + threadIdx.x;   // 131072 total
  int a = idx >> 11, j = idx & 2047;
  const float4* s = (const float4*)(Bsrc + (((size_t)a << 11) + j) * RANK);
  float4 f0 = s[0], f1 = s[1], f2 = s[2], f3 = s[3];
  us8* d = (us8*)(WB + (size_t)j * KTOT + H + a * RANK);
  d[0] = pack8(f0, f1);
  d[1] = pack8(f2, f3);
}

// Per token: arrows = sumsq over r, top-4 adapters, G row = routes*v.
__global__ void route_kernel(const float* __restrict__ vecs,
                             unsigned short* __restrict__ XG) {
  __shared__ float vsh[4][16];
  int wave = threadIdx.x >> 6, lane = threadIdx.x & 63;
  int t = blockIdx.x * 4 + wave;
  const float* vrow = vecs + (size_t)t * KG;
  const float4* vp = (const float4*)(vrow + lane * RANK);
  float4 q0 = vp[0], q1 = vp[1], q2 = vp[2], q3 = vp[3];
  float ss = q0.x*q0.x + q0.y*q0.y + q0.z*q0.z + q0.w*q0.w
           + q1.x*q1.x + q1.y*q1.y + q1.z*q1.z + q1.w*q1.w
           + q2.x*q2.x + q2.y*q2.y + q2.z*q2.z + q2.w*q2.w
           + q3.x*q3.x + q3.y*q3.y + q3.z*q3.z + q3.w*q3.w;
  float arr = ss;
  int sel[4];
  #pragma unroll
  for (int k = 0; k < 4; ++k) {
    float m = arr; int mi = lane;
    #pragma unroll
    for (int o = 32; o > 0; o >>= 1) {
      float om = __shfl_xor(m, o);
      int oi  = __shfl_xor(mi, o);
      if (om > m || (om == m && oi < mi)) { m = om; mi = oi; }
    }
    sel[k] = mi;                 // wave-uniform
    if (lane == mi) arr = -3.0e38f;
  }
  if (lane < 16) {
    float s = vrow[sel[0]*RANK + lane] + vrow[sel[1]*RANK + lane]
            + vrow[sel[2]*RANK + lane] + vrow[sel[3]*RANK + lane];
    vsh[wave][lane] = 0.0625f * s;
  }
  __syncthreads();
  bool on = (lane == sel[0]) | (lane == sel[1]) | (lane == sel[2]) | (lane == sel[3]);
  us8 lo, hi;
  #pragma unroll
  for (int r = 0; r < 8; ++r) lo[r] = on ? f2bf(vsh[wave][r])     : (unsigned short)0;
  #pragma unroll
  for (int r = 0; r < 8; ++r) hi[r] = on ? f2bf(vsh[wave][r + 8]) : (unsigned short)0;
  us8* d = (us8*)(XG + (size_t)t * KTOT + H + lane * RANK);
  d[0] = lo; d[1] = hi;
}

__device__ __forceinline__ void gload_lds16(const void* gsrc, void* ldst) {
  __builtin_amdgcn_global_load_lds(
      (const __attribute__((address_space(1))) unsigned int*)gsrc,
      (__attribute__((address_space(3))) unsigned int*)ldst, 16, 0, 0);
}

// Shared schedule helpers
#define BAR() asm volatile("s_waitcnt lgkmcnt(0)\n\ts_barrier" ::: "memory")
#define VM2() asm volatile("s_waitcnt vmcnt(2)" ::: "memory")
#define VM3() asm volatile("s_waitcnt vmcnt(3)" ::: "memory")
#define VM8() asm volatile("s_waitcnt vmcnt(8)" ::: "memory")
#define P1() __builtin_amdgcn_s_setprio(1)
#define P0() __builtin_amdgcn_s_setprio(0)

// ------------------------------------------------------------------
// GEMM1 (3-term split): vecs[8192,1024] = Xhi@Ahi^T + Xhi@Alo^T + Xlo@Ahi^T.
// BM=256, BN=128, BK=32, 512 thr (8 waves 4Mx2N, per-wave 64x64).
// LDS per buf: XH 16K | XL 16K | AH 8K | AL 8K (=48K, x2 = 96K).
// 3 phases/K-tile, 16 MFMA per phase, 2 stage-units/phase, counted vmcnt.
// Swizzle: 16B slot ^= (row>>1)&3 on stage-src and ds_read (both sides).
// XCD map: bm-pinned (per-XCD working set ~16MB).
// ------------------------------------------------------------------
#define MM1(mi, xf, bv) do {                                                   \
  acc[mi][0] = __builtin_amdgcn_mfma_f32_16x16x32_bf16(xf, bv[0], acc[mi][0], 0, 0, 0); \
  acc[mi][1] = __builtin_amdgcn_mfma_f32_16x16x32_bf16(xf, bv[1], acc[mi][1], 0, 0, 0); \
  acc[mi][2] = __builtin_amdgcn_mfma_f32_16x16x32_bf16(xf, bv[2], acc[mi][2], 0, 0, 0); \
  acc[mi][3] = __builtin_amdgcn_mfma_f32_16x16x32_bf16(xf, bv[3], acc[mi][3], 0, 0, 0); \
} while (0)

#define LD1(off) (*(const v8bf*)(Lb + (off)))

#define S_XH1(b, kel) gload_lds16(XhB + (size_t)srow * KTOT + (kel) + scol, Lb + (b)*49152 + tid*16)
#define S_XH2(b, kel) gload_lds16(XhB + (size_t)(srow + 128) * KTOT + (kel) + scol, Lb + (b)*49152 + 8192 + tid*16)
#define S_XL1(b, kel) gload_lds16(XlB + (size_t)srow * H + (kel) + scol, Lb + (b)*49152 + 16384 + tid*16)
#define S_XL2(b, kel) gload_lds16(XlB + (size_t)(srow + 128) * H + (kel) + scol, Lb + (b)*49152 + 24576 + tid*16)
#define S_AH1(b, kel) gload_lds16(AhB + (size_t)srow * H + (kel) + scol, Lb + (b)*49152 + 32768 + tid*16)
#define S_AL1(b, kel) gload_lds16(AlB + (size_t)srow * H + (kel) + scol, Lb + (b)*49152 + 40960 + tid*16)

#define TILE1(c, n, kn) do {                                                   \
  /* p0: hi*hi, mi 0..3 */                                                     \
  xh[0] = LD1((c)*49152 + abyte);                                              \
  xh[1] = LD1((c)*49152 + abyte + 1024);                                       \
  xh[2] = LD1((c)*49152 + abyte + 2048);                                       \
  xh[3] = LD1((c)*49152 + abyte + 3072);                                       \
  ah[0] = LD1((c)*49152 + 32768 + bbyte);                                      \
  ah[1] = LD1((c)*49152 + 32768 + bbyte + 1024);                               \
  ah[2] = LD1((c)*49152 + 32768 + bbyte + 2048);                               \
  ah[3] = LD1((c)*49152 + 32768 + bbyte + 3072);                               \
  S_XH1(n, kn); S_XH2(n, kn);                                                  \
  BAR(); P1(); MM1(0, xh[0], ah); MM1(1, xh[1], ah);                           \
               MM1(2, xh[2], ah); MM1(3, xh[3], ah); P0(); VM2(); BAR();       \
  /* p1: hi*lo, mi 0..3 */                                                     \
  al[0] = LD1((c)*49152 + 40960 + bbyte);                                      \
  al[1] = LD1((c)*49152 + 40960 + bbyte + 1024);                               \
  al[2] = LD1((c)*49152 + 40960 + bbyte + 2048);                               \
  al[3] = LD1((c)*49152 + 40960 + bbyte + 3072);                               \
  S_AH1(n, kn); S_XL1(n, kn);                                                  \
  BAR(); P1(); MM1(0, xh[0], al); MM1(1, xh[1], al);                           \
               MM1(2, xh[2], al); MM1(3, xh[3], al); P0(); BAR();              \
  /* p2: lo*hi, mi 0..3 */                                                     \
  xl[0] = LD1((c)*49152 + 16384 + abyte);                                      \
  xl[1] = LD1((c)*49152 + 16384 + abyte + 1024);                               \
  xl[2] = LD1((c)*49152 + 16384 + abyte + 2048);                               \
  xl[3] = LD1((c)*49152 + 16384 + abyte + 3072);                               \
  S_XL2(n, kn); S_AL1(n, kn);                                                  \
  BAR(); P1(); MM1(0, xl[0], ah); MM1(1, xl[1], ah);                           \
               MM1(2, xl[2], ah); MM1(3, xl[3], ah); P0(); VM3(); BAR();       \
} while (0)

__global__ __launch_bounds__(512, 1) void gemm1_8ph_kernel(
    const unsigned short* __restrict__ Xhi,   // stride KTOT (hi block of XG)
    const unsigned short* __restrict__ Xlo,   // stride H
    const unsigned short* __restrict__ Ahi,   // stride H
    const unsigned short* __restrict__ Alo,   // stride H
    float* __restrict__ C) {                  // [8192][1024]
  __shared__ char Ls[98304];                  // 96 KB
  char* Lb = Ls;
  const int tid = threadIdx.x;
  const int lane = tid & 63, wid = tid >> 6;
  const int wr = wid >> 1, wc = wid & 1;      // 4M x 2N waves, 64x64 each
  const int rA = lane & 15, grp = lane >> 4;
  const int grpx = (grp ^ ((rA >> 1) & 3)) << 4;

  const int bid = blockIdx.x;
  const int g = bid & 7, r = bid >> 3;
  const int bm = g * 4 + (r & 3), bn = r >> 2;  // bm-pinned per XCD

  const unsigned short* XhB = Xhi + (size_t)(bm * 256) * KTOT;
  const unsigned short* XlB = Xlo + (size_t)(bm * 256) * H;
  const unsigned short* AhB = Ahi + (size_t)(bn * 128) * H;
  const unsigned short* AlB = Alo + (size_t)(bn * 128) * H;

  const int srow = tid >> 2;
  const int scol = ((tid & 3) ^ ((tid >> 3) & 3)) << 3;   // pre-swizzled src slot

  const int abyte = (wr * 64 + rA) * 64 + grpx;   // within XH/XL (+mi*1024)
  const int bbyte = (wc * 64 + rA) * 64 + grpx;   // within AH/AL (+nj*1024)

  v4f acc[4][4];
  #pragma unroll
  for (int i = 0; i < 4; ++i)
    #pragma unroll
    for (int j = 0; j < 4; ++j)
      acc[i][j] = (v4f){0.f, 0.f, 0.f, 0.f};
  v8bf xh[4], xl[4], ah[4], al[4];

  // prologue: stage tile 0, queue order [XH1,XH2,AH,XL1,XL2,AL]
  S_XH1(0, 0); S_XH2(0, 0); S_AH1(0, 0); S_XL1(0, 0); S_XL2(0, 0); S_AL1(0, 0);
  VM3(); BAR();

  #pragma unroll 1
  for (int t = 0; t < NT1; t += 2) {
    const int ka = (t + 1) * 32;                         // stage for tile t+1
    const int kb = (t + 2 < NT1 ? t + 2 : NT1 - 1) * 32; // stage for t+2 (clamped)
    TILE1(0, 1, ka);
    TILE1(1, 0, kb);
  }

  const int row0 = bm * 256 + wr * 64 + (grp << 2);
  const int col0 = bn * 128 + wc * 64 + rA;
  #pragma unroll
  for (int mi = 0; mi < 4; ++mi)
    #pragma unroll
    for (int j = 0; j < 4; ++j)
      #pragma unroll
      for (int q = 0; q < 4; ++q)
        C[(size_t)(row0 + mi * 16 + q) * KG + col0 + j * 16] = acc[mi][j][q];
}

// ------------------------------------------------------------------
// GEMM2: out[8192,2048] = XG[8192,3072]@WB[2048,3072]^T + bias.
// 256x256 tile, BK=64, 8 waves, 8-phase, counted vmcnt(8), setprio, swizzle.
// XCD map: bm-pinned (was bn-pinned; per-XCD L2-miss set 50MB -> 18MB).
// ------------------------------------------------------------------
#define STAGE(regionUS, panel, kelem) do {                                        \
  gload_lds16((panel) + aoff0 + (kelem), (char*)(regionUS) + tid * 16);           \
  gload_lds16((panel) + aoff1 + (kelem), (char*)(regionUS) + 8192 + tid * 16);    \
} while (0)

#define PHASE(mh, RAr, RBr, ISSUE, DOVM) do {                                     \
  if ((mh) == 0) {                                                                \
    _Pragma("unroll")                                                             \
    for (int j = 0; j < 4; ++j)                                                   \
      bfr[j] = *(const v8bf*)((const char*)(RBr) + bbyte + j * 1024);             \
  }                                                                               \
  _Pragma("unroll")                                                               \
  for (int i = 0; i < 4; ++i)                                                     \
    af[i] = *(const v8bf*)((const char*)(RAr) + abyte + ((mh)*4 + i) * 1024);     \
  ISSUE;                                                                          \
  BAR();                                                                          \
  P1();                                                                           \
  _Pragma("unroll")                                                               \
  for (int i = 0; i < 4; ++i)                                                     \
    _Pragma("unroll")                                                             \
    for (int j = 0; j < 4; ++j)                                                   \
      acc[(mh)*4 + i][j] = __builtin_amdgcn_mfma_f32_16x16x32_bf16(               \
          af[i], bfr[j], acc[(mh)*4 + i][j], 0, 0, 0);                            \
  P0();                                                                           \
  DOVM;                                                                           \
  BAR();                                                                          \
} while (0)

__global__ __launch_bounds__(512, 1) void gemm2_8ph_kernel(
    const unsigned short* __restrict__ Xg, const unsigned short* __restrict__ Wb,
    float* __restrict__ C, const float* __restrict__ bias) {
  __shared__ unsigned short lds[65536];   // 128 KB
  const int tid = threadIdx.x;
  const int lane = tid & 63, wid = tid >> 6;
  const int wr = wid >> 2, wc = wid & 3;
  const int rA = lane & 15, grp = lane >> 4;
  const int grpx = (grp ^ ((rA >> 1) & 3)) << 4;   // swizzled 16B slot (byte)

  const int bid = blockIdx.x;
  const int g = bid & 7, r = bid >> 3;
  const int bm = g * 4 + (r & 3), bn = r >> 2;     // bm-pinned per XCD

  const unsigned short* Ap = Xg + (size_t)(bm * 256) * KTOT;
  const unsigned short* Bp = Wb + (size_t)(bn * 256) * KTOT;

  const int srow = tid >> 2;
  const int scol = ((tid & 3) ^ ((tid >> 3) & 3)) << 3;
  const size_t aoff0 = (size_t)srow * KTOT + scol;
  const size_t aoff1 = (size_t)(srow + 128) * KTOT + scol;

  unsigned short* A0k0 = lds;
  unsigned short* A0k1 = lds + 8192;
  unsigned short* B0k0 = lds + 16384;
  unsigned short* B0k1 = lds + 24576;
  unsigned short* A1k0 = lds + 32768;
  unsigned short* A1k1 = lds + 40960;
  unsigned short* B1k0 = lds + 49152;
  unsigned short* B1k1 = lds + 57344;

  const int abyte = (wr * 128 + rA) * 64 + grpx;
  const int bbyte = (wc * 64 + rA) * 64 + grpx;

  v4f acc[8][4];
  #pragma unroll
  for (int i = 0; i < 8; ++i)
    #pragma unroll
    for (int j = 0; j < 4; ++j)
      acc[i][j] = (v4f){0.f, 0.f, 0.f, 0.f};
  v8bf af[4], bfr[4];

  STAGE(A0k0, Ap, 0);
  STAGE(B0k0, Bp, 0);
  STAGE(A0k1, Ap, 32);
  STAGE(B0k1, Bp, 32);
  STAGE(A1k0, Ap, 64);
  STAGE(B1k0, Bp, 64);
  VM8();
  BAR();

  #pragma unroll 1
  for (int t = 0; t < NT2; t += 2) {
    const int k1a = (t + 1) * 64 + 32;
    const int k0a = (t + 2 < NT2 ? t + 2 : NT2 - 1) * 64;
    const int k1b = (t + 2 < NT2 ? t + 2 : NT2 - 1) * 64 + 32;
    const int k0b = (t + 3 < NT2 ? t + 3 : NT2 - 1) * 64;
    PHASE(0, A0k0, B0k0, STAGE(A1k1, Ap, k1a), ((void)0));
    PHASE(1, A0k0, B0k0, STAGE(B1k1, Bp, k1a), VM8());
    PHASE(0, A0k1, B0k1, STAGE(A0k0, Ap, k0a), ((void)0));
    PHASE(1, A0k1, B0k1, STAGE(B0k0, Bp, k0a), VM8());
    PHASE(0, A1k0, B1k0, STAGE(A0k1, Ap, k1b), ((void)0));
    PHASE(1, A1k0, B1k0, STAGE(B0k1, Bp, k1b), VM8());
    PHASE(0, A1k1, B1k1, STAGE(A1k0, Ap, k0b), ((void)0));
    PHASE(1, A1k1, B1k1, STAGE(B1k0, Bp, k0b), VM8());
  }

  const int row0 = bm * 256 + wr * 128 + (grp << 2);
  const int col0 = bn * 256 + wc * 64 + rA;
  float bv[4];
  #pragma unroll
  for (int j = 0; j < 4; ++j) bv[j] = bias[col0 + j * 16];
  #pragma unroll
  for (int mi = 0; mi < 8; ++mi)
    #pragma unroll
    for (int j = 0; j < 4; ++j)
      #pragma unroll
      for (int q = 0; q < 4; ++q)
        C[(size_t)(row0 + mi * 16 + q) * JDIM + col0 + j * 16] = acc[mi][j][q] + bv[j];
}

extern "C" void kernel_launch(void* const* d_in, const int* in_sizes, int n_in,
                              void* d_out, int out_size, void* d_ws, size_t ws_size,
                              hipStream_t stream) {
  const float* x    = (const float*)d_in[0];
  const float* A    = (const float*)d_in[1];
  const float* Bb   = (const float*)d_in[2];
  const float* W    = (const float*)d_in[3];
  const float* bias = (const float*)d_in[4];
  float* out = (float*)d_out;

  char* ws = (char*)d_ws;
  // ws layout: XG bf16 [8192][3072] (48M) | WB bf16 [2048][3072] (12M) |
  //            Ahi bf16 [1024][2048] (4M) | Alo bf16 [1024][2048] (4M)   = 68M
  unsigned short* XG  = (unsigned short*)ws;
  unsigned short* WB  = (unsigned short*)(ws + (size_t)48 * 1024 * 1024);
  unsigned short* Ahi = (unsigned short*)(ws + (size_t)60 * 1024 * 1024);
  unsigned short* Alo = (unsigned short*)(ws + (size_t)64 * 1024 * 1024);
  // d_out doubles as pre-gemm2 scratch: lower 32MB vecs f32, upper 32MB x_lo bf16.
  float* vecs         = (float*)d_out;
  unsigned short* XLO = (unsigned short*)((char*)d_out + (size_t)32 * 1024 * 1024);

  cast_x_split_kernel<<<TOKENS, 256, 0, stream>>>(x, XG, XLO);
  cast_a_split_kernel<<<KG, 256, 0, stream>>>(A, Ahi, Alo);
  cast2048_kernel<<<JDIM, 256, 0, stream>>>(W, WB, KTOT);
  cast_b_kernel<<<512, 256, 0, stream>>>(Bb, WB);

  // vecs = x @ A^T in near-fp32 (3-term bf16 split), 3-phase counted-vmcnt schedule
  gemm1_8ph_kernel<<<256, 512, 0, stream>>>(XG, XLO, Ahi, Alo, vecs);

  // routing -> G block of XG
  route_kernel<<<TOKENS / 4, 256, 0, stream>>>(vecs, XG);

  // out = [Xb|G] @ [Wb|Bt]^T + bias   (M=8192, N=2048, K=3072), 8-phase 256² tile
  gemm2_8ph_kernel<<<256, 512, 0, stream>>>(XG, WB, out, bias);
}

// Round 10
// 213.150 us; speedup vs baseline: 1.3098x; 1.0416x over previous
//
#include <hip/hip_runtime.h>
#include <hip/hip_bf16.h>
#include <stdint.h>

// Shapes (fixed for this problem)
#define TOKENS 8192   // b*s = 4*2048
#define H 2048
#define JDIM 2048
#define NADAPT 64
#define RANK 16
#define KG 1024       // NADAPT*RANK
#define KTOT 3072     // H + KG
#define NT2 48        // gemm2 K-tiles = KTOT/64
#define NT1 64        // gemm1 K-tiles = H/32

typedef __bf16 v8bf __attribute__((ext_vector_type(8)));
typedef float v4f __attribute__((ext_vector_type(4)));
typedef unsigned short us8 __attribute__((ext_vector_type(8)));
typedef unsigned short us4 __attribute__((ext_vector_type(4)));

__device__ __forceinline__ unsigned short f2bf(float f) {
  union { __bf16 b; unsigned short u; } c; c.b = (__bf16)f; return c.u;
}
__device__ __forceinline__ float bf2f(unsigned short u) {
  union { unsigned int u; float f; } c; c.u = ((unsigned int)u) << 16; return c.f;
}

__device__ __forceinline__ us8 pack8(float4 a, float4 b) {
  us8 r;
  r[0]=f2bf(a.x); r[1]=f2bf(a.y); r[2]=f2bf(a.z); r[3]=f2bf(a.w);
  r[4]=f2bf(b.x); r[5]=f2bf(b.y); r[6]=f2bf(b.z); r[7]=f2bf(b.w);
  return r;
}

__device__ __forceinline__ void split8(float4 a, float4 b, us8& h, us8& l) {
  float v[8] = {a.x, a.y, a.z, a.w, b.x, b.y, b.z, b.w};
  #pragma unroll
  for (int i = 0; i < 8; ++i) {
    h[i] = f2bf(v[i]);
    l[i] = f2bf(v[i] - bf2f(h[i]));
  }
}

// x fp32 [8192][2048] -> hi bf16 into XG (stride KTOT), lo bf16 into XLO (stride 2048).
__global__ void cast_x_split_kernel(const float* __restrict__ x,
                                    unsigned short* __restrict__ XG,
                                    unsigned short* __restrict__ XLO) {
  int idx = blockIdx.x * 256 + threadIdx.x;
  int row = idx >> 8;
  int cg  = idx & 255;
  const float4* s = (const float4*)(x + ((size_t)row << 11) + ((size_t)cg << 3));
  float4 a = s[0], b = s[1];
  us8 h, l;
  split8(a, b, h, l);
  *(us8*)(XG  + (size_t)row * KTOT + ((size_t)cg << 3)) = h;
  *(us8*)(XLO + (size_t)row * H    + ((size_t)cg << 3)) = l;
}

// A fp32 [1024][2048] -> Ahi, Alo bf16 [1024][2048].
__global__ void cast_a_split_kernel(const float* __restrict__ A,
                                    unsigned short* __restrict__ Ahi,
                                    unsigned short* __restrict__ Alo) {
  int idx = blockIdx.x * 256 + threadIdx.x;
  int row = idx >> 8;
  int cg  = idx & 255;
  const float4* s = (const float4*)(A + ((size_t)row << 11) + ((size_t)cg << 3));
  float4 a = s[0], b = s[1];
  us8 h, l;
  split8(a, b, h, l);
  *(us8*)(Ahi + (size_t)row * H + ((size_t)cg << 3)) = h;
  *(us8*)(Alo + (size_t)row * H + ((size_t)cg << 3)) = l;
}

// fp32 [rows][2048] -> bf16 [rows][dstld] (fills cols 0..2047).
__global__ void cast2048_kernel(const float* __restrict__ src,
                                unsigned short* __restrict__ dst, int dstld) {
  int idx = blockIdx.x * 256 + threadIdx.x;
  int row = idx >> 8;
  int cg  = idx & 255;
  const float4* s = (const float4*)(src + ((size_t)row << 11) + ((size_t)cg << 3));
  float4 a = s[0], b = s[1];
  *(us8*)(dst + (size_t)row * dstld + ((size_t)cg << 3)) = pack8(a, b);
}

// B [64][2048][16] fp32 -> WB[j][2048 + a*16 + r] bf16. One thread per (a,j).
__global__ void cast_b_kernel(const float* __restrict__ Bsrc,
                              unsigned short* __restrict__ WB) {
  int idx = blockIdx.x * 256 + threadIdx.x;   // 131072 total
  int a = idx >> 11, j = idx & 2047;
  const float4* s = (const float4*)(Bsrc + (((size_t)a << 11) + j) * RANK);
  float4 f0 = s[0], f1 = s[1], f2 = s[2], f3 = s[3];
  us8* d = (us8*)(WB + (size_t)j * KTOT + H + a * RANK);
  d[0] = pack8(f0, f1);
  d[1] = pack8(f2, f3);
}

// Per token: arrows = sumsq over r, top-4 adapters, G row = routes*v.
__global__ void route_kernel(const float* __restrict__ vecs,
                             unsigned short* __restrict__ XG) {
  __shared__ float vsh[4][16];
  int wave = threadIdx.x >> 6, lane = threadIdx.x & 63;
  int t = blockIdx.x * 4 + wave;
  const float* vrow = vecs + (size_t)t * KG;
  const float4* vp = (const float4*)(vrow + lane * RANK);
  float4 q0 = vp[0], q1 = vp[1], q2 = vp[2], q3 = vp[3];
  float ss = q0.x*q0.x + q0.y*q0.y + q0.z*q0.z + q0.w*q0.w
           + q1.x*q1.x + q1.y*q1.y + q1.z*q1.z + q1.w*q1.w
           + q2.x*q2.x + q2.y*q2.y + q2.z*q2.z + q2.w*q2.w
           + q3.x*q3.x + q3.y*q3.y + q3.z*q3.z + q3.w*q3.w;
  float arr = ss;
  int sel[4];
  #pragma unroll
  for (int k = 0; k < 4; ++k) {
    float m = arr; int mi = lane;
    #pragma unroll
    for (int o = 32; o > 0; o >>= 1) {
      float om = __shfl_xor(m, o);
      int oi  = __shfl_xor(mi, o);
      if (om > m || (om == m && oi < mi)) { m = om; mi = oi; }
    }
    sel[k] = mi;                 // wave-uniform
    if (lane == mi) arr = -3.0e38f;
  }
  if (lane < 16) {
    float s = vrow[sel[0]*RANK + lane] + vrow[sel[1]*RANK + lane]
            + vrow[sel[2]*RANK + lane] + vrow[sel[3]*RANK + lane];
    vsh[wave][lane] = 0.0625f * s;
  }
  __syncthreads();
  bool on = (lane == sel[0]) | (lane == sel[1]) | (lane == sel[2]) | (lane == sel[3]);
  us8 lo, hi;
  #pragma unroll
  for (int r = 0; r < 8; ++r) lo[r] = on ? f2bf(vsh[wave][r])     : (unsigned short)0;
  #pragma unroll
  for (int r = 0; r < 8; ++r) hi[r] = on ? f2bf(vsh[wave][r + 8]) : (unsigned short)0;
  us8* d = (us8*)(XG + (size_t)t * KTOT + H + lane * RANK);
  d[0] = lo; d[1] = hi;
}

__device__ __forceinline__ void gload_lds16(const void* gsrc, void* ldst) {
  __builtin_amdgcn_global_load_lds(
      (const __attribute__((address_space(1))) unsigned int*)gsrc,
      (__attribute__((address_space(3))) unsigned int*)ldst, 16, 0, 0);
}

// Shared schedule helpers
#define BAR()  asm volatile("s_waitcnt lgkmcnt(0)\n\ts_barrier" ::: "memory")  // prologue only
#define BARO() asm volatile("s_barrier" ::: "memory")   // loop barrier: LDS reads may stay in flight
#define VM4() asm volatile("s_waitcnt vmcnt(4)" ::: "memory")
#define VM6() asm volatile("s_waitcnt vmcnt(6)" ::: "memory")
#define VM8() asm volatile("s_waitcnt vmcnt(8)" ::: "memory")
#define P1() __builtin_amdgcn_s_setprio(1)
#define P0() __builtin_amdgcn_s_setprio(0)

// ------------------------------------------------------------------
// GEMM1 (3-term split, read-ahead pipeline): vecs = Xhi@Ahi^T + Xhi@Alo^T + Xlo@Ahi^T.
// BM=256, BN=128, BK=32, 512 thr (8 waves 4Mx2N, 64x64/wave).
// 3 LDS buffers x 48KB (XH 16K | XL 16K | AH 8K | AL 8K) = 144KB, rotating;
// stage tile t+2 during tile t (2 units/phase). Frag reads for phase p+1 issue
// during phase p (overlap MFMA/LDS pipes); guard = VM4 + barrier each phase end
// (stage-to-read distance >= 4 phases). Accumulation order per element: hh,hl,lh
// per K-tile -- identical to previous rounds (bit-identical output).
// ------------------------------------------------------------------
#define MM1(mi, xf, bv) do {                                                   \
  acc[mi][0] = __builtin_amdgcn_mfma_f32_16x16x32_bf16(xf, bv[0], acc[mi][0], 0, 0, 0); \
  acc[mi][1] = __builtin_amdgcn_mfma_f32_16x16x32_bf16(xf, bv[1], acc[mi][1], 0, 0, 0); \
  acc[mi][2] = __builtin_amdgcn_mfma_f32_16x16x32_bf16(xf, bv[2], acc[mi][2], 0, 0, 0); \
  acc[mi][3] = __builtin_amdgcn_mfma_f32_16x16x32_bf16(xf, bv[3], acc[mi][3], 0, 0, 0); \
} while (0)

#define S_XH1(B, kel) gload_lds16(XhB + (size_t)srow * KTOT + (kel) + scol, (B) + tid*16)
#define S_XH2(B, kel) gload_lds16(XhB + (size_t)(srow + 128) * KTOT + (kel) + scol, (B) + 8192 + tid*16)
#define S_XL1(B, kel) gload_lds16(XlB + (size_t)srow * H + (kel) + scol, (B) + 16384 + tid*16)
#define S_XL2(B, kel) gload_lds16(XlB + (size_t)(srow + 128) * H + (kel) + scol, (B) + 24576 + tid*16)
#define S_AH1(B, kel) gload_lds16(AhB + (size_t)srow * H + (kel) + scol, (B) + 32768 + tid*16)
#define S_AL1(B, kel) gload_lds16(AlB + (size_t)srow * H + (kel) + scol, (B) + 40960 + tid*16)

__global__ __launch_bounds__(512, 1) void gemm1_8ph_kernel(
    const unsigned short* __restrict__ Xhi,   // stride KTOT (hi block of XG)
    const unsigned short* __restrict__ Xlo,   // stride H
    const unsigned short* __restrict__ Ahi,   // stride H
    const unsigned short* __restrict__ Alo,   // stride H
    float* __restrict__ C) {                  // [8192][1024]
  __shared__ char Ls[147456];                 // 3 x 48KB
  const int tid = threadIdx.x;
  const int lane = tid & 63, wid = tid >> 6;
  const int wr = wid >> 1, wc = wid & 1;      // 4M x 2N waves, 64x64 each
  const int rA = lane & 15, grp = lane >> 4;
  const int grpx = (grp ^ ((rA >> 1) & 3)) << 4;

  const int bid = blockIdx.x;
  const int g = bid & 7, r = bid >> 3;
  const int bm = g * 4 + (r & 3), bn = r >> 2;  // bm-pinned per XCD

  const unsigned short* XhB = Xhi + (size_t)(bm * 256) * KTOT;
  const unsigned short* XlB = Xlo + (size_t)(bm * 256) * H;
  const unsigned short* AhB = Ahi + (size_t)(bn * 128) * H;
  const unsigned short* AlB = Alo + (size_t)(bn * 128) * H;

  const int srow = tid >> 2;
  const int scol = ((tid & 3) ^ ((tid >> 3) & 3)) << 3;   // pre-swizzled src slot

  const int abyte = (wr * 64 + rA) * 64 + grpx;   // within XH/XL (+mi*1024)
  const int bbyte = (wc * 64 + rA) * 64 + grpx;   // within AH/AL (+nj*1024)

  char* bufA = Ls;            // tile t (current reads)
  char* bufB = Ls + 49152;    // tile t+1
  char* bufC = Ls + 98304;    // tile t+2 (stage target)

  v4f acc[4][4];
  #pragma unroll
  for (int i = 0; i < 4; ++i)
    #pragma unroll
    for (int j = 0; j < 4; ++j)
      acc[i][j] = (v4f){0.f, 0.f, 0.f, 0.f};
  v8bf xh[4], xl[4], ah[4], al[4];

  // prologue: stage tiles 0 and 1 fully
  S_XH1(bufA, 0); S_XH2(bufA, 0); S_AH1(bufA, 0); S_XL1(bufA, 0); S_XL2(bufA, 0); S_AL1(bufA, 0);
  S_XH1(bufB, 32); S_XH2(bufB, 32); S_AH1(bufB, 32); S_XL1(bufB, 32); S_XL2(bufB, 32); S_AL1(bufB, 32);
  VM8(); BAR();
  // preload p0 frags of tile 0
  #pragma unroll
  for (int i = 0; i < 4; ++i) xh[i] = *(const v8bf*)(bufA + abyte + i * 1024);
  #pragma unroll
  for (int j = 0; j < 4; ++j) ah[j] = *(const v8bf*)(bufA + 32768 + bbyte + j * 1024);

  #pragma unroll 1
  for (int t = 0; t < NT1; ++t) {
    const int kel = (t + 2 < NT1 ? t + 2 : NT1 - 1) * 32;
    // p0: hi*hi  | read al (for p1) | stage XH(t+2)
    P1(); MM1(0, xh[0], ah); MM1(1, xh[1], ah); MM1(2, xh[2], ah); MM1(3, xh[3], ah); P0();
    #pragma unroll
    for (int j = 0; j < 4; ++j) al[j] = *(const v8bf*)(bufA + 40960 + bbyte + j * 1024);
    S_XH1(bufC, kel); S_XH2(bufC, kel);
    VM4(); BARO();
    // p1: hi*lo  | read xl (for p2) | stage AH,XL1(t+2)
    P1(); MM1(0, xh[0], al); MM1(1, xh[1], al); MM1(2, xh[2], al); MM1(3, xh[3], al); P0();
    #pragma unroll
    for (int i = 0; i < 4; ++i) xl[i] = *(const v8bf*)(bufA + 16384 + abyte + i * 1024);
    S_AH1(bufC, kel); S_XL1(bufC, kel);
    VM4(); BARO();
    // p2: lo*hi  | read xh,ah of next tile (for p0') | stage XL2,AL(t+2)
    P1(); MM1(0, xl[0], ah); MM1(1, xl[1], ah); MM1(2, xl[2], ah); MM1(3, xl[3], ah); P0();
    #pragma unroll
    for (int i = 0; i < 4; ++i) xh[i] = *(const v8bf*)(bufB + abyte + i * 1024);
    #pragma unroll
    for (int j = 0; j < 4; ++j) ah[j] = *(const v8bf*)(bufB + 32768 + bbyte + j * 1024);
    S_XL2(bufC, kel); S_AL1(bufC, kel);
    VM4(); BARO();
    // rotate buffers
    char* tmp = bufA; bufA = bufB; bufB = bufC; bufC = tmp;
  }

  const int row0 = bm * 256 + wr * 64 + (grp << 2);
  const int col0 = bn * 128 + wc * 64 + rA;
  #pragma unroll
  for (int mi = 0; mi < 4; ++mi)
    #pragma unroll
    for (int j = 0; j < 4; ++j)
      #pragma unroll
      for (int q = 0; q < 4; ++q)
        C[(size_t)(row0 + mi * 16 + q) * KG + col0 + j * 16] = acc[mi][j][q];
}

// ------------------------------------------------------------------
// GEMM2 (read-ahead pipeline): out = XG @ WB^T + bias. 256x256, BK=64, 8 waves.
// Frag reads for phase p+1 issue during phase p (A double-buffered afA/afB,
// B single bfr re-read on even phases). One barrier/phase; uniform VM6 at
// phase end (stage-to-read >= 4 phases). XCD map bm-pinned. Swizzle unchanged.
// ------------------------------------------------------------------
#define STAGE(regionUS, panel, kelem) do {                                        \
  gload_lds16((panel) + aoff0 + (kelem), (char*)(regionUS) + tid * 16);           \
  gload_lds16((panel) + aoff1 + (kelem), (char*)(regionUS) + 8192 + tid * 16);    \
} while (0)

// odd phase (mh0): MFMA acc[0..3] with AFC/bfr; read A mh1 rows of RAn into AFN
#define PH2A(AFC, RAn, AFN, STG) do {                                             \
  P1();                                                                           \
  _Pragma("unroll")                                                               \
  for (int i = 0; i < 4; ++i)                                                     \
    _Pragma("unroll")                                                             \
    for (int j = 0; j < 4; ++j)                                                   \
      acc[i][j] = __builtin_amdgcn_mfma_f32_16x16x32_bf16(                        \
          AFC[i], bfr[j], acc[i][j], 0, 0, 0);                                    \
  P0();                                                                           \
  _Pragma("unroll")                                                               \
  for (int i = 0; i < 4; ++i)                                                     \
    AFN[i] = *(const v8bf*)((const char*)(RAn) + abyte + (4 + i) * 1024);         \
  STG;                                                                            \
  VM6(); BARO();                                                                  \
} while (0)

// even phase (mh1): MFMA acc[4..7]; read B region RBn into bfr + A mh0 of RAn
#define PH2B(AFC, RBn, RAn, AFN, STG) do {                                        \
  P1();                                                                           \
  _Pragma("unroll")                                                               \
  for (int i = 0; i < 4; ++i)                                                     \
    _Pragma("unroll")                                                             \
    for (int j = 0; j < 4; ++j)                                                   \
      acc[4 + i][j] = __builtin_amdgcn_mfma_f32_16x16x32_bf16(                    \
          AFC[i], bfr[j], acc[4 + i][j], 0, 0, 0);                                \
  P0();                                                                           \
  _Pragma("unroll")                                                               \
  for (int j = 0; j < 4; ++j)                                                     \
    bfr[j] = *(const v8bf*)((const char*)(RBn) + bbyte + j * 1024);               \
  _Pragma("unroll")                                                               \
  for (int i = 0; i < 4; ++i)                                                     \
    AFN[i] = *(const v8bf*)((const char*)(RAn) + abyte + i * 1024);               \
  STG;                                                                            \
  VM6(); BARO();                                                                  \
} while (0)

__global__ __launch_bounds__(512, 1) void gemm2_8ph_kernel(
    const unsigned short* __restrict__ Xg, const unsigned short* __restrict__ Wb,
    float* __restrict__ C, const float* __restrict__ bias) {
  __shared__ unsigned short lds[65536];   // 128 KB
  const int tid = threadIdx.x;
  const int lane = tid & 63, wid = tid >> 6;
  const int wr = wid >> 2, wc = wid & 3;
  const int rA = lane & 15, grp = lane >> 4;
  const int grpx = (grp ^ ((rA >> 1) & 3)) << 4;   // swizzled 16B slot (byte)

  const int bid = blockIdx.x;
  const int g = bid & 7, r = bid >> 3;
  const int bm = g * 4 + (r & 3), bn = r >> 2;     // bm-pinned per XCD

  const unsigned short* Ap = Xg + (size_t)(bm * 256) * KTOT;
  const unsigned short* Bp = Wb + (size_t)(bn * 256) * KTOT;

  const int srow = tid >> 2;
  const int scol = ((tid & 3) ^ ((tid >> 3) & 3)) << 3;
  const size_t aoff0 = (size_t)srow * KTOT + scol;
  const size_t aoff1 = (size_t)(srow + 128) * KTOT + scol;

  unsigned short* A0k0 = lds;
  unsigned short* A0k1 = lds + 8192;
  unsigned short* B0k0 = lds + 16384;
  unsigned short* B0k1 = lds + 24576;
  unsigned short* A1k0 = lds + 32768;
  unsigned short* A1k1 = lds + 40960;
  unsigned short* B1k0 = lds + 49152;
  unsigned short* B1k1 = lds + 57344;

  const int abyte = (wr * 128 + rA) * 64 + grpx;
  const int bbyte = (wc * 64 + rA) * 64 + grpx;

  v4f acc[8][4];
  #pragma unroll
  for (int i = 0; i < 8; ++i)
    #pragma unroll
    for (int j = 0; j < 4; ++j)
      acc[i][j] = (v4f){0.f, 0.f, 0.f, 0.f};
  v8bf afA[4], afB[4], bfr[4];

  // prologue: 6 regions (FIFO: A0k0,B0k0,A0k1,B0k1,A1k0,B1k0)
  STAGE(A0k0, Ap, 0);
  STAGE(B0k0, Bp, 0);
  STAGE(A0k1, Ap, 32);
  STAGE(B0k1, Bp, 32);
  STAGE(A1k0, Ap, 64);
  STAGE(B1k0, Bp, 64);
  VM8();
  BAR();
  // preload phase-1 frags: A0k0 mh0 + B0k0
  #pragma unroll
  for (int i = 0; i < 4; ++i) afA[i] = *(const v8bf*)((const char*)A0k0 + abyte + i * 1024);
  #pragma unroll
  for (int j = 0; j < 4; ++j) bfr[j] = *(const v8bf*)((const char*)B0k0 + bbyte + j * 1024);

  #pragma unroll 1
  for (int t = 0; t < NT2; t += 2) {
    const int k1a = (t + 1) * 64 + 32;
    const int k0a = (t + 2 < NT2 ? t + 2 : NT2 - 1) * 64;
    const int k1b = (t + 2 < NT2 ? t + 2 : NT2 - 1) * 64 + 32;
    const int k0b = (t + 3 < NT2 ? t + 3 : NT2 - 1) * 64;
    PH2A(afA, A0k0, afB, STAGE(A1k1, Ap, k1a));          // p1: MFMA A0k0/B0k0 mh0
    PH2B(afB, B0k1, A0k1, afA, STAGE(B1k1, Bp, k1a));    // p2: mh1; read B0k1,A0k1mh0
    PH2A(afA, A0k1, afB, STAGE(A0k0, Ap, k0a));          // p3
    PH2B(afB, B1k0, A1k0, afA, STAGE(B0k0, Bp, k0a));    // p4
    PH2A(afA, A1k0, afB, STAGE(A0k1, Ap, k1b));          // p5
    PH2B(afB, B1k1, A1k1, afA, STAGE(B0k1, Bp, k1b));    // p6
    PH2A(afA, A1k1, afB, STAGE(A1k0, Ap, k0b));          // p7
    PH2B(afB, B0k0, A0k0, afA, STAGE(B1k0, Bp, k0b));    // p8
  }

  const int row0 = bm * 256 + wr * 128 + (grp << 2);
  const int col0 = bn * 256 + wc * 64 + rA;
  float bv[4];
  #pragma unroll
  for (int j = 0; j < 4; ++j) bv[j] = bias[col0 + j * 16];
  #pragma unroll
  for (int mi = 0; mi < 8; ++mi)
    #pragma unroll
    for (int j = 0; j < 4; ++j)
      #pragma unroll
      for (int q = 0; q < 4; ++q)
        C[(size_t)(row0 + mi * 16 + q) * JDIM + col0 + j * 16] = acc[mi][j][q] + bv[j];
}

extern "C" void kernel_launch(void* const* d_in, const int* in_sizes, int n_in,
                              void* d_out, int out_size, void* d_ws, size_t ws_size,
                              hipStream_t stream) {
  const float* x    = (const float*)d_in[0];
  const float* A    = (const float*)d_in[1];
  const float* Bb   = (const float*)d_in[2];
  const float* W    = (const float*)d_in[3];
  const float* bias = (const float*)d_in[4];
  float* out = (float*)d_out;

  char* ws = (char*)d_ws;
  // ws layout: XG bf16 [8192][3072] (48M) | WB bf16 [2048][3072] (12M) |
  //            Ahi bf16 [1024][2048] (4M) | Alo bf16 [1024][2048] (4M)   = 68M
  unsigned short* XG  = (unsigned short*)ws;
  unsigned short* WB  = (unsigned short*)(ws + (size_t)48 * 1024 * 1024);
  unsigned short* Ahi = (unsigned short*)(ws + (size_t)60 * 1024 * 1024);
  unsigned short* Alo = (unsigned short*)(ws + (size_t)64 * 1024 * 1024);
  // d_out doubles as pre-gemm2 scratch: lower 32MB vecs f32, upper 32MB x_lo bf16.
  float* vecs         = (float*)d_out;
  unsigned short* XLO = (unsigned short*)((char*)d_out + (size_t)32 * 1024 * 1024);

  cast_x_split_kernel<<<TOKENS, 256, 0, stream>>>(x, XG, XLO);
  cast_a_split_kernel<<<KG, 256, 0, stream>>>(A, Ahi, Alo);
  cast2048_kernel<<<JDIM, 256, 0, stream>>>(W, WB, KTOT);
  cast_b_kernel<<<512, 256, 0, stream>>>(Bb, WB);

  // vecs = x @ A^T in near-fp32 (3-term bf16 split), read-ahead pipeline
  gemm1_8ph_kernel<<<256, 512, 0, stream>>>(XG, XLO, Ahi, Alo, vecs);

  // routing -> G block of XG
  route_kernel<<<TOKENS / 4, 256, 0, stream>>>(vecs, XG);

  // out = [Xb|G] @ [Wb|Bt]^T + bias, read-ahead 8-phase 256² tile
  gemm2_8ph_kernel<<<256, 512, 0, stream>>>(XG, WB, out, bias);
}

// Round 11
// 212.016 us; speedup vs baseline: 1.3168x; 1.0054x over previous
//
#include <hip/hip_runtime.h>
#include <hip/hip_bf16.h>
#include <stdint.h>

// Shapes (fixed for this problem)
#define TOKENS 8192   // b*s = 4*2048
#define H 2048
#define JDIM 2048
#define NADAPT 64
#define RANK 16
#define KG 1024       // NADAPT*RANK
#define KTOT 3072     // H + KG
#define NT2 48        // gemm2 K-tiles = KTOT/64
#define NT1 64        // gemm1 K-tiles = H/32

typedef __bf16 v8bf __attribute__((ext_vector_type(8)));
typedef float v4f __attribute__((ext_vector_type(4)));
typedef unsigned short us8 __attribute__((ext_vector_type(8)));
typedef unsigned short us4 __attribute__((ext_vector_type(4)));

__device__ __forceinline__ unsigned short f2bf(float f) {
  union { __bf16 b; unsigned short u; } c; c.b = (__bf16)f; return c.u;
}
__device__ __forceinline__ float bf2f(unsigned short u) {
  union { unsigned int u; float f; } c; c.u = ((unsigned int)u) << 16; return c.f;
}

__device__ __forceinline__ us8 pack8(float4 a, float4 b) {
  us8 r;
  r[0]=f2bf(a.x); r[1]=f2bf(a.y); r[2]=f2bf(a.z); r[3]=f2bf(a.w);
  r[4]=f2bf(b.x); r[5]=f2bf(b.y); r[6]=f2bf(b.z); r[7]=f2bf(b.w);
  return r;
}

__device__ __forceinline__ void split8(float4 a, float4 b, us8& h, us8& l) {
  float v[8] = {a.x, a.y, a.z, a.w, b.x, b.y, b.z, b.w};
  #pragma unroll
  for (int i = 0; i < 8; ++i) {
    h[i] = f2bf(v[i]);
    l[i] = f2bf(v[i] - bf2f(h[i]));
  }
}

// All input casts in one launch. Blocks [0,8192): x split -> XG hi + XLO;
// [8192,9216): A split -> Ahi/Alo; [9216,11264): W -> WB; [11264,11776): B -> WB.
__global__ void cast_all_kernel(const float* __restrict__ x,
                                const float* __restrict__ A,
                                const float* __restrict__ W,
                                const float* __restrict__ Bsrc,
                                unsigned short* __restrict__ XG,
                                unsigned short* __restrict__ XLO,
                                unsigned short* __restrict__ Ahi,
                                unsigned short* __restrict__ Alo,
                                unsigned short* __restrict__ WB) {
  int bid = blockIdx.x;
  int cg = threadIdx.x;
  if (bid < TOKENS) {                         // x rows
    int row = bid;
    const float4* s = (const float4*)(x + ((size_t)row << 11) + ((size_t)cg << 3));
    float4 a = s[0], b = s[1];
    us8 h, l;
    split8(a, b, h, l);
    *(us8*)(XG  + (size_t)row * KTOT + ((size_t)cg << 3)) = h;
    *(us8*)(XLO + (size_t)row * H    + ((size_t)cg << 3)) = l;
  } else if (bid < TOKENS + KG) {             // A rows
    int row = bid - TOKENS;
    const float4* s = (const float4*)(A + ((size_t)row << 11) + ((size_t)cg << 3));
    float4 a = s[0], b = s[1];
    us8 h, l;
    split8(a, b, h, l);
    *(us8*)(Ahi + ((size_t)row << 11) + ((size_t)cg << 3)) = h;
    *(us8*)(Alo + ((size_t)row << 11) + ((size_t)cg << 3)) = l;
  } else if (bid < TOKENS + KG + JDIM) {      // W rows
    int row = bid - TOKENS - KG;
    const float4* s = (const float4*)(W + ((size_t)row << 11) + ((size_t)cg << 3));
    float4 a = s[0], b = s[1];
    *(us8*)(WB + (size_t)row * KTOT + ((size_t)cg << 3)) = pack8(a, b);
  } else {                                    // B: one thread per (a,j)
    int idx = (bid - TOKENS - KG - JDIM) * 256 + cg;  // 131072 total
    int a = idx >> 11, j = idx & 2047;
    const float4* s = (const float4*)(Bsrc + (((size_t)a << 11) + j) * RANK);
    float4 f0 = s[0], f1 = s[1], f2 = s[2], f3 = s[3];
    us8* d = (us8*)(WB + (size_t)j * KTOT + H + a * RANK);
    d[0] = pack8(f0, f1);
    d[1] = pack8(f2, f3);
  }
}

// Per token: arrows = sumsq over r, top-4 adapters, G row = routes*v.
__global__ void route_kernel(const float* __restrict__ vecs,
                             unsigned short* __restrict__ XG) {
  __shared__ float vsh[4][16];
  int wave = threadIdx.x >> 6, lane = threadIdx.x & 63;
  int t = blockIdx.x * 4 + wave;
  const float* vrow = vecs + (size_t)t * KG;
  const float4* vp = (const float4*)(vrow + lane * RANK);
  float4 q0 = vp[0], q1 = vp[1], q2 = vp[2], q3 = vp[3];
  float ss = q0.x*q0.x + q0.y*q0.y + q0.z*q0.z + q0.w*q0.w
           + q1.x*q1.x + q1.y*q1.y + q1.z*q1.z + q1.w*q1.w
           + q2.x*q2.x + q2.y*q2.y + q2.z*q2.z + q2.w*q2.w
           + q3.x*q3.x + q3.y*q3.y + q3.z*q3.z + q3.w*q3.w;
  float arr = ss;
  int sel[4];
  #pragma unroll
  for (int k = 0; k < 4; ++k) {
    float m = arr; int mi = lane;
    #pragma unroll
    for (int o = 32; o > 0; o >>= 1) {
      float om = __shfl_xor(m, o);
      int oi  = __shfl_xor(mi, o);
      if (om > m || (om == m && oi < mi)) { m = om; mi = oi; }
    }
    sel[k] = mi;                 // wave-uniform
    if (lane == mi) arr = -3.0e38f;
  }
  if (lane < 16) {
    float s = vrow[sel[0]*RANK + lane] + vrow[sel[1]*RANK + lane]
            + vrow[sel[2]*RANK + lane] + vrow[sel[3]*RANK + lane];
    vsh[wave][lane] = 0.0625f * s;
  }
  __syncthreads();
  bool on = (lane == sel[0]) | (lane == sel[1]) | (lane == sel[2]) | (lane == sel[3]);
  us8 lo, hi;
  #pragma unroll
  for (int r = 0; r < 8; ++r) lo[r] = on ? f2bf(vsh[wave][r])     : (unsigned short)0;
  #pragma unroll
  for (int r = 0; r < 8; ++r) hi[r] = on ? f2bf(vsh[wave][r + 8]) : (unsigned short)0;
  us8* d = (us8*)(XG + (size_t)t * KTOT + H + lane * RANK);
  d[0] = lo; d[1] = hi;
}

__device__ __forceinline__ void gload_lds16(const void* gsrc, void* ldst) {
  __builtin_amdgcn_global_load_lds(
      (const __attribute__((address_space(1))) unsigned int*)gsrc,
      (__attribute__((address_space(3))) unsigned int*)ldst, 16, 0, 0);
}

// Shared schedule helpers
#define BAR()  asm volatile("s_waitcnt vmcnt(0) lgkmcnt(0)\n\ts_barrier" ::: "memory")  // prologue
#define BARO() asm volatile("s_barrier" ::: "memory")   // loop barrier
#define VM4() asm volatile("s_waitcnt vmcnt(4)" ::: "memory")
#define P1() __builtin_amdgcn_s_setprio(1)
#define P0() __builtin_amdgcn_s_setprio(0)

// ------------------------------------------------------------------
// GEMM1 (3-term split, read-ahead): vecs = Xhi@Ahi^T + Xhi@Alo^T + Xlo@Ahi^T.
// BM=256, BN=128, BK=32, 512 thr (8 waves 4Mx2N, 64x64/wave).
// 3 rotating LDS bufs x 48KB; stage tile t+2 during tile t (2 units/phase).
// ahA/ahB double-buffered per tile (next-tile ah read never clashes with
// current MFMA's ah registers). Barriers: end-p1, end-p2 only, VM4 each
// (= 2 phases' stages outstanding; all stage->read distances >= 5 phases).
// Accumulation order per element (hh,hl,lh per K-tile) identical -> bit-identical.
// ------------------------------------------------------------------
#define MM1(mi, xf, bv) do {                                                   \
  acc[mi][0] = __builtin_amdgcn_mfma_f32_16x16x32_bf16(xf, bv[0], acc[mi][0], 0, 0, 0); \
  acc[mi][1] = __builtin_amdgcn_mfma_f32_16x16x32_bf16(xf, bv[1], acc[mi][1], 0, 0, 0); \
  acc[mi][2] = __builtin_amdgcn_mfma_f32_16x16x32_bf16(xf, bv[2], acc[mi][2], 0, 0, 0); \
  acc[mi][3] = __builtin_amdgcn_mfma_f32_16x16x32_bf16(xf, bv[3], acc[mi][3], 0, 0, 0); \
} while (0)

#define S_XH1(B, kel) gload_lds16(XhB + (size_t)srow * KTOT + (kel) + scol, (B) + tid*16)
#define S_XH2(B, kel) gload_lds16(XhB + (size_t)(srow + 128) * KTOT + (kel) + scol, (B) + 8192 + tid*16)
#define S_XL1(B, kel) gload_lds16(XlB + (size_t)srow * H + (kel) + scol, (B) + 16384 + tid*16)
#define S_XL2(B, kel) gload_lds16(XlB + (size_t)(srow + 128) * H + (kel) + scol, (B) + 24576 + tid*16)
#define S_AH1(B, kel) gload_lds16(AhB + (size_t)srow * H + (kel) + scol, (B) + 32768 + tid*16)
#define S_AL1(B, kel) gload_lds16(AlB + (size_t)srow * H + (kel) + scol, (B) + 40960 + tid*16)

#define TILE1(AHC, AHN, kel) do {                                              \
  /* p0: hi*hi | read al (p1) | stage XH(t+2) | no barrier */                  \
  P1(); MM1(0, xh[0], AHC); MM1(1, xh[1], AHC);                                \
        MM1(2, xh[2], AHC); MM1(3, xh[3], AHC); P0();                          \
  _Pragma("unroll")                                                            \
  for (int j = 0; j < 4; ++j) al[j] = *(const v8bf*)(bufA + 40960 + bbyte + j * 1024); \
  S_XH1(bufC, kel); S_XH2(bufC, kel);                                          \
  /* p1: hi*lo | read xl (p2) | stage AH,XL1(t+2) */                           \
  P1(); MM1(0, xh[0], al); MM1(1, xh[1], al);                                  \
        MM1(2, xh[2], al); MM1(3, xh[3], al); P0();                            \
  _Pragma("unroll")                                                            \
  for (int i = 0; i < 4; ++i) xl[i] = *(const v8bf*)(bufA + 16384 + abyte + i * 1024); \
  S_AH1(bufC, kel); S_XL1(bufC, kel);                                          \
  VM4(); BARO();                                                               \
  /* p2: lo*hi | read xh,AHN of next tile | stage XL2,AL(t+2) */               \
  P1(); MM1(0, xl[0], AHC); MM1(1, xl[1], AHC);                                \
        MM1(2, xl[2], AHC); MM1(3, xl[3], AHC); P0();                          \
  _Pragma("unroll")                                                            \
  for (int i = 0; i < 4; ++i) xh[i] = *(const v8bf*)(bufB + abyte + i * 1024); \
  _Pragma("unroll")                                                            \
  for (int j = 0; j < 4; ++j) AHN[j] = *(const v8bf*)(bufB + 32768 + bbyte + j * 1024); \
  S_XL2(bufC, kel); S_AL1(bufC, kel);                                          \
  VM4(); BARO();                                                               \
  { char* tmp_ = bufA; bufA = bufB; bufB = bufC; bufC = tmp_; }                \
} while (0)

__global__ __launch_bounds__(512, 1) void gemm1_8ph_kernel(
    const unsigned short* __restrict__ Xhi,   // stride KTOT (hi block of XG)
    const unsigned short* __restrict__ Xlo,   // stride H
    const unsigned short* __restrict__ Ahi,   // stride H
    const unsigned short* __restrict__ Alo,   // stride H
    float* __restrict__ C) {                  // [8192][1024]
  __shared__ char Ls[147456];                 // 3 x 48KB
  const int tid = threadIdx.x;
  const int lane = tid & 63, wid = tid >> 6;
  const int wr = wid >> 1, wc = wid & 1;      // 4M x 2N waves, 64x64 each
  const int rA = lane & 15, grp = lane >> 4;
  const int grpx = (grp ^ ((rA >> 1) & 3)) << 4;

  const int bid = blockIdx.x;
  const int g = bid & 7, r = bid >> 3;
  const int bm = g * 4 + (r & 3), bn = r >> 2;  // bm-pinned per XCD

  const unsigned short* XhB = Xhi + (size_t)(bm * 256) * KTOT;
  const unsigned short* XlB = Xlo + (size_t)(bm * 256) * H;
  const unsigned short* AhB = Ahi + (size_t)(bn * 128) * H;
  const unsigned short* AlB = Alo + (size_t)(bn * 128) * H;

  const int srow = tid >> 2;
  const int scol = ((tid & 3) ^ ((tid >> 3) & 3)) << 3;   // pre-swizzled src slot

  const int abyte = (wr * 64 + rA) * 64 + grpx;   // within XH/XL (+mi*1024)
  const int bbyte = (wc * 64 + rA) * 64 + grpx;   // within AH/AL (+nj*1024)

  char* bufA = Ls;            // tile t (current reads)
  char* bufB = Ls + 49152;    // tile t+1
  char* bufC = Ls + 98304;    // tile t+2 (stage target)

  v4f acc[4][4];
  #pragma unroll
  for (int i = 0; i < 4; ++i)
    #pragma unroll
    for (int j = 0; j < 4; ++j)
      acc[i][j] = (v4f){0.f, 0.f, 0.f, 0.f};
  v8bf xh[4], xl[4], al[4], ahA[4], ahB_[4];

  // prologue: stage tiles 0 and 1 fully; full drain; preload p0 frags of tile 0
  S_XH1(bufA, 0); S_XH2(bufA, 0); S_AH1(bufA, 0); S_XL1(bufA, 0); S_XL2(bufA, 0); S_AL1(bufA, 0);
  S_XH1(bufB, 32); S_XH2(bufB, 32); S_AH1(bufB, 32); S_XL1(bufB, 32); S_XL2(bufB, 32); S_AL1(bufB, 32);
  BAR();
  #pragma unroll
  for (int i = 0; i < 4; ++i) xh[i] = *(const v8bf*)(bufA + abyte + i * 1024);
  #pragma unroll
  for (int j = 0; j < 4; ++j) ahA[j] = *(const v8bf*)(bufA + 32768 + bbyte + j * 1024);

  #pragma unroll 1
  for (int t = 0; t < NT1; t += 2) {
    const int ka = (t + 2 < NT1 ? t + 2 : NT1 - 1) * 32;
    const int kb = (t + 3 < NT1 ? t + 3 : NT1 - 1) * 32;
    TILE1(ahA, ahB_, ka);
    TILE1(ahB_, ahA, kb);
  }

  const int row0 = bm * 256 + wr * 64 + (grp << 2);
  const int col0 = bn * 128 + wc * 64 + rA;
  #pragma unroll
  for (int mi = 0; mi < 4; ++mi)
    #pragma unroll
    for (int j = 0; j < 4; ++j)
      #pragma unroll
      for (int q = 0; q < 4; ++q)
        C[(size_t)(row0 + mi * 16 + q) * KG + col0 + j * 16] = acc[mi][j][q];
}

// ------------------------------------------------------------------
// GEMM2 (read-ahead, paired phases): out = XG @ WB^T + bias. 256x256, BK=64,
// 8 waves. afA/afB AND bfrA/bfrB double-buffered -> every ds_read issues
// concurrently with MFMA. Barrier + VM4 every 2 phases (derived: all
// stage->read distances >= 4 phases, all WAR pairs separated by >= 1 barrier).
// ------------------------------------------------------------------
#define STAGE(regionUS, panel, kelem) do {                                        \
  gload_lds16((panel) + aoff0 + (kelem), (char*)(regionUS) + tid * 16);           \
  gload_lds16((panel) + aoff1 + (kelem), (char*)(regionUS) + 8192 + tid * 16);    \
} while (0)

// odd phase: MFMA acc[0..3] = AFC x BFC; read AFN <- RA mh1, BFN <- RB; stage
#define PHO(AFC, BFC, RA, AFN, RB, BFN, STG) do {                                 \
  P1();                                                                           \
  _Pragma("unroll")                                                               \
  for (int i = 0; i < 4; ++i)                                                     \
    _Pragma("unroll")                                                             \
    for (int j = 0; j < 4; ++j)                                                   \
      acc[i][j] = __builtin_amdgcn_mfma_f32_16x16x32_bf16(                        \
          AFC[i], BFC[j], acc[i][j], 0, 0, 0);                                    \
  P0();                                                                           \
  _Pragma("unroll")                                                               \
  for (int i = 0; i < 4; ++i)                                                     \
    AFN[i] = *(const v8bf*)((const char*)(RA) + abyte + (4 + i) * 1024);          \
  _Pragma("unroll")                                                               \
  for (int j = 0; j < 4; ++j)                                                     \
    BFN[j] = *(const v8bf*)((const char*)(RB) + bbyte + j * 1024);                \
  STG;                                                                            \
} while (0)

// even phase: MFMA acc[4..7] = AFC x BFC; read AFN <- RA mh0; stage; VM4+bar
#define PHE(AFC, BFC, RA, AFN, STG) do {                                          \
  P1();                                                                           \
  _Pragma("unroll")                                                               \
  for (int i = 0; i < 4; ++i)                                                     \
    _Pragma("unroll")                                                             \
    for (int j = 0; j < 4; ++j)                                                   \
      acc[4 + i][j] = __builtin_amdgcn_mfma_f32_16x16x32_bf16(                    \
          AFC[i], BFC[j], acc[4 + i][j], 0, 0, 0);                                \
  P0();                                                                           \
  _Pragma("unroll")                                                               \
  for (int i = 0; i < 4; ++i)                                                     \
    AFN[i] = *(const v8bf*)((const char*)(RA) + abyte + i * 1024);                \
  STG;                                                                            \
  VM4(); BARO();                                                                  \
} while (0)

__global__ __launch_bounds__(512, 1) void gemm2_8ph_kernel(
    const unsigned short* __restrict__ Xg, const unsigned short* __restrict__ Wb,
    float* __restrict__ C, const float* __restrict__ bias) {
  __shared__ unsigned short lds[65536];   // 128 KB
  const int tid = threadIdx.x;
  const int lane = tid & 63, wid = tid >> 6;
  const int wr = wid >> 2, wc = wid & 3;
  const int rA = lane & 15, grp = lane >> 4;
  const int grpx = (grp ^ ((rA >> 1) & 3)) << 4;   // swizzled 16B slot (byte)

  const int bid = blockIdx.x;
  const int g = bid & 7, r = bid >> 3;
  const int bm = g * 4 + (r & 3), bn = r >> 2;     // bm-pinned per XCD

  const unsigned short* Ap = Xg + (size_t)(bm * 256) * KTOT;
  const unsigned short* Bp = Wb + (size_t)(bn * 256) * KTOT;

  const int srow = tid >> 2;
  const int scol = ((tid & 3) ^ ((tid >> 3) & 3)) << 3;
  const size_t aoff0 = (size_t)srow * KTOT + scol;
  const size_t aoff1 = (size_t)(srow + 128) * KTOT + scol;

  unsigned short* A0k0 = lds;
  unsigned short* A0k1 = lds + 8192;
  unsigned short* B0k0 = lds + 16384;
  unsigned short* B0k1 = lds + 24576;
  unsigned short* A1k0 = lds + 32768;
  unsigned short* A1k1 = lds + 40960;
  unsigned short* B1k0 = lds + 49152;
  unsigned short* B1k1 = lds + 57344;

  const int abyte = (wr * 128 + rA) * 64 + grpx;
  const int bbyte = (wc * 64 + rA) * 64 + grpx;

  v4f acc[8][4];
  #pragma unroll
  for (int i = 0; i < 8; ++i)
    #pragma unroll
    for (int j = 0; j < 4; ++j)
      acc[i][j] = (v4f){0.f, 0.f, 0.f, 0.f};
  v8bf afA[4], afB[4], bfrA[4], bfrB[4];

  // prologue: 6 regions; full drain; preload afA (A0k0 mh0) + bfrA (B0k0)
  STAGE(A0k0, Ap, 0);
  STAGE(B0k0, Bp, 0);
  STAGE(A0k1, Ap, 32);
  STAGE(B0k1, Bp, 32);
  STAGE(A1k0, Ap, 64);
  STAGE(B1k0, Bp, 64);
  BAR();
  #pragma unroll
  for (int i = 0; i < 4; ++i) afA[i] = *(const v8bf*)((const char*)A0k0 + abyte + i * 1024);
  #pragma unroll
  for (int j = 0; j < 4; ++j) bfrA[j] = *(const v8bf*)((const char*)B0k0 + bbyte + j * 1024);

  #pragma unroll 1
  for (int t = 0; t < NT2; t += 2) {
    const int k1a = (t + 1) * 64 + 32;
    const int k0a = (t + 2 < NT2 ? t + 2 : NT2 - 1) * 64;
    const int k1b = (t + 2 < NT2 ? t + 2 : NT2 - 1) * 64 + 32;
    const int k0b = (t + 3 < NT2 ? t + 3 : NT2 - 1) * 64;
    PHO(afA, bfrA, A0k0, afB, B0k1, bfrB, STAGE(A1k1, Ap, k1a));  // p1
    PHE(afB, bfrA, A0k1, afA, STAGE(B1k1, Bp, k1a));              // p2 +bar
    PHO(afA, bfrB, A0k1, afB, B1k0, bfrA, STAGE(A0k0, Ap, k0a));  // p3
    PHE(afB, bfrB, A1k0, afA, STAGE(B0k0, Bp, k0a));              // p4 +bar
    PHO(afA, bfrA, A1k0, afB, B1k1, bfrB, STAGE(A0k1, Ap, k1b));  // p5
    PHE(afB, bfrA, A1k1, afA, STAGE(B0k1, Bp, k1b));              // p6 +bar
    PHO(afA, bfrB, A1k1, afB, B0k0, bfrA, STAGE(A1k0, Ap, k0b));  // p7
    PHE(afB, bfrB, A0k0, afA, STAGE(B1k0, Bp, k0b));              // p8 +bar
  }

  const int row0 = bm * 256 + wr * 128 + (grp << 2);
  const int col0 = bn * 256 + wc * 64 + rA;
  float bv[4];
  #pragma unroll
  for (int j = 0; j < 4; ++j) bv[j] = bias[col0 + j * 16];
  #pragma unroll
  for (int mi = 0; mi < 8; ++mi)
    #pragma unroll
    for (int j = 0; j < 4; ++j)
      #pragma unroll
      for (int q = 0; q < 4; ++q)
        C[(size_t)(row0 + mi * 16 + q) * JDIM + col0 + j * 16] = acc[mi][j][q] + bv[j];
}

extern "C" void kernel_launch(void* const* d_in, const int* in_sizes, int n_in,
                              void* d_out, int out_size, void* d_ws, size_t ws_size,
                              hipStream_t stream) {
  const float* x    = (const float*)d_in[0];
  const float* A    = (const float*)d_in[1];
  const float* Bb   = (const float*)d_in[2];
  const float* W    = (const float*)d_in[3];
  const float* bias = (const float*)d_in[4];
  float* out = (float*)d_out;

  char* ws = (char*)d_ws;
  // ws layout: XG bf16 [8192][3072] (48M) | WB bf16 [2048][3072] (12M) |
  //            Ahi bf16 [1024][2048] (4M) | Alo bf16 [1024][2048] (4M)   = 68M
  unsigned short* XG  = (unsigned short*)ws;
  unsigned short* WB  = (unsigned short*)(ws + (size_t)48 * 1024 * 1024);
  unsigned short* Ahi = (unsigned short*)(ws + (size_t)60 * 1024 * 1024);
  unsigned short* Alo = (unsigned short*)(ws + (size_t)64 * 1024 * 1024);
  // d_out doubles as pre-gemm2 scratch: lower 32MB vecs f32, upper 32MB x_lo bf16.
  float* vecs         = (float*)d_out;
  unsigned short* XLO = (unsigned short*)((char*)d_out + (size_t)32 * 1024 * 1024);

  // all casts in one launch (x, A, W, B sections)
  cast_all_kernel<<<TOKENS + KG + JDIM + 512, 256, 0, stream>>>(
      x, A, W, Bb, XG, XLO, Ahi, Alo, WB);

  // vecs = x @ A^T in near-fp32 (3-term bf16 split), read-ahead pipeline
  gemm1_8ph_kernel<<<256, 512, 0, stream>>>(XG, XLO, Ahi, Alo, vecs);

  // routing -> G block of XG
  route_kernel<<<TOKENS / 4, 256, 0, stream>>>(vecs, XG);

  // out = [Xb|G] @ [Wb|Bt]^T + bias, read-ahead paired-phase 256² tile
  gemm2_8ph_kernel<<<256, 512, 0, stream>>>(XG, WB, out, bias);
}